// Round 4
// baseline (962.049 us; speedup 1.0000x reference)
//
#include <hip/hip_runtime.h>
#include <cstdint>

#define NF 65536
#define PL 8
#define NL 4096
#define PPL 128
#define XKS 64  // padded xk record stride (floats): 256 B, cacheline-aligned

__device__ __forceinline__ float sigm(float v) { return 1.0f / (1.0f + __expf(-v)); }
__device__ __forceinline__ float tanhfast(float v) {
    float e = __expf(2.0f * v);
    return 1.0f - 2.0f / (e + 1.0f);
}
__device__ __forceinline__ float seluf(float x) {
    return x > 0.0f ? 1.0507009873554805f * x : 1.7580993408473766f * (__expf(x) - 1.0f);
}
__device__ __forceinline__ unsigned short f2bf(float x) {
    unsigned u = __float_as_uint(x);
    u += 0x7fffu + ((u >> 16) & 1u);
    return (unsigned short)(u >> 16);
}
__device__ __forceinline__ float bflo(unsigned u) { return __uint_as_float(u << 16); }
__device__ __forceinline__ float bfhi(unsigned u) { return __uint_as_float(u & 0xffff0000u); }

// Sparse cubic B-spline: 4 active bases at local u, interval idx. Uniform knots
// t_j = (j-3)*0.4 - 1 (identical to jnp _knots pyramid; closed-form is exact).
__device__ __forceinline__ int bspline4(float xx, float& B0, float& B1, float& B2,
                                        float& B3) {
    const float KN0 = (0 - 3) * 0.4f - 1.0f;    // t_0  = -2.2
    float s = (xx - KN0) * 2.5f;
    int idx = (int)floorf(s);
    bool valid = (idx >= 0) && (idx <= 10);     // outside [t_0, t_11): all bases 0
    idx = min(max(idx, 0), 10);
    float tI = (float)(idx - 3) * 0.4f - 1.0f;
    float u = (xx - tI) * 2.5f;
    float um = 1.0f - u;
    float u2 = u * u, u3 = u2 * u;
    B0 = um * um * um * (1.0f / 6.0f);
    B1 = 0.5f * u3 - u2 + (2.0f / 3.0f);
    B2 = -0.5f * u3 + 0.5f * u2 + 0.5f * u + (1.0f / 6.0f);
    B3 = u3 * (1.0f / 6.0f);
    if (!valid) { B0 = 0.f; B1 = 0.f; B2 = 0.f; B3 = 0.f; }
    return idx;
}

// ---------------- S1: per-link load ----------------
__global__ __launch_bounds__(256) void k_load(const int* __restrict__ p2l,
                                              const float* __restrict__ ft,
                                              const float* __restrict__ cap,
                                              float* __restrict__ load) {
    int gid = blockIdx.x * 256 + threadIdx.x;
    int link = gid >> 6;
    int lane = threadIdx.x & 63;
    const int2* b2 = (const int2*)(p2l + (size_t)link * PPL * 2);
    int2 v0 = b2[lane];
    int2 v1 = b2[lane + 64];
    float s = ft[v0.x] + ft[v1.x];
#pragma unroll
    for (int off = 32; off; off >>= 1) s += __shfl_xor(s, off);
    if (lane == 0) load[link] = s / (cap[link] * 1e9f);
}

// ---------------- S2: flow encoder -> path_state ----------------
__global__ __launch_bounds__(256) void k_flow_enc(
    const float* __restrict__ tr, const float* __restrict__ pk,
    const float* __restrict__ ppb, const float* __restrict__ bpb,
    const float* __restrict__ psz, const float* __restrict__ p90,
    const float* __restrict__ rate, const float* __restrict__ ipgm,
    const float* __restrict__ ibg, const float* __restrict__ ipgv,
    const float* __restrict__ ftype, const int* __restrict__ flen,
    const float* __restrict__ w1, const float* __restrict__ b1,
    const float* __restrict__ w2, const float* __restrict__ b2,
    float* __restrict__ ps) {
    __shared__ float sw1[13 * 16], sb1[16], sw2[256], sb2[16];
    int tid = threadIdx.x;
    if (tid < 208) sw1[tid] = w1[tid];
    sw2[tid] = w2[tid];
    if (tid < 16) { sb1[tid] = b1[tid]; sb2[tid] = b2[tid]; }
    __syncthreads();
    int f = blockIdx.x * 256 + tid;
    float feat[13];
    feat[0] = (tr[f] - 0.5f) * 2.0f;
    feat[1] = (pk[f] - 0.5f) * 2.0f;
    feat[2] = (ibg[f] - 0.5f) * 2.0f;
    feat[3] = (rate[f] - 0.5f) * 2.0f;
    feat[4] = (p90[f] - 0.5f) * 2.0f;
    feat[5] = (psz[f] - 0.5f) * 2.0f;
    feat[6] = (bpb[f] - 0.5f) * 2.0f;
    feat[7] = (ipgm[f] - 0.5f) * 2.0f;
    feat[8] = (ipgv[f] - 0.5f) * 2.0f;
    feat[9] = (ppb[f] - 0.5f) * 2.0f;
    feat[10] = (float)flen[f];
    float2 ft2 = ((const float2*)ftype)[f];
    feat[11] = ft2.x;
    feat[12] = ft2.y;
    float t1[16];
#pragma unroll
    for (int u = 0; u < 16; ++u) {
        float a = sb1[u];
#pragma unroll
        for (int i = 0; i < 13; ++i) a += feat[i] * sw1[i * 16 + u];
        t1[u] = seluf(a);
    }
    float out[16];
#pragma unroll
    for (int u = 0; u < 16; ++u) {
        float a = sb2[u];
#pragma unroll
        for (int i = 0; i < 16; ++i) a += t1[i] * sw2[i * 16 + u];
        out[u] = seluf(a);
    }
    float4* o4 = (float4*)(ps + (size_t)f * 16);
    const float4* s4 = (const float4*)out;
#pragma unroll
    for (int q = 0; q < 4; ++q) o4[q] = s4[q];
}

// ---------------- S3: link encoder -> link_state (+ xk fold) ----------------
__global__ __launch_bounds__(256) void k_link_enc(
    const float* __restrict__ cap, const float* __restrict__ load,
    const float* __restrict__ mll,
    const float* __restrict__ w1, const float* __restrict__ b1,
    const float* __restrict__ w2, const float* __restrict__ b2,
    float* __restrict__ ls, float* __restrict__ xk,
    const float* __restrict__ pgk, const float* __restrict__ pgb) {
    int l = blockIdx.x * 256 + threadIdx.x;
    if (l >= NL) return;
    float f0 = (cap[l] - 5.0f) * 0.25f;
    float f1 = load[l];
    float f2 = f1 / mll[0];
    float f3 = 8.0f / 32768.0f;
    float t1[16];
#pragma unroll
    for (int u = 0; u < 16; ++u) {
        float a = b1[u] + f0 * w1[u] + f1 * w1[16 + u] + f2 * w1[32 + u] + f3 * w1[48 + u];
        t1[u] = seluf(a);
    }
    float out[16];
#pragma unroll
    for (int u = 0; u < 16; ++u) {
        float a = b2[u];
#pragma unroll
        for (int i = 0; i < 16; ++i) a += t1[i] * w2[i * 16 + u];
        out[u] = seluf(a);
    }
    float4* o4 = (float4*)(ls + (size_t)l * 16);
    const float4* s4 = (const float4*)out;
#pragma unroll
    for (int q = 0; q < 4; ++q) o4[q] = s4[q];
    for (int u = 0; u < 48; ++u) {
        float a = pgb[u];
#pragma unroll
        for (int i = 0; i < 16; ++i) a += out[i] * pgk[i * 48 + u];
        xk[(size_t)l * XKS + u] = a;
    }
}

// ---------------- K1: path GRU, 4 threads per flow ----------------
// MODE 0: f32 seq [f][9][16] rows 0..8; MODE 1: bf16 seq [t][NF][16] rows 0..7;
// MODE 2: f32 seqF [f][8][16] rows 1..8 (KAN input)
template <int MODE>
__global__ __launch_bounds__(256) void k_path4(
    const float* __restrict__ xk, const int* __restrict__ ltp,
    float* __restrict__ ps, unsigned short* __restrict__ seqb,
    float* __restrict__ seqf,
    const float* __restrict__ grk, const float* __restrict__ gb) {
    __shared__ float srk[768], sbg[48];
    int tid = threadIdx.x;
    for (int i = tid; i < 768; i += 256) srk[i] = grk[i];
    if (tid < 48) sbg[tid] = gb[48 + tid];
    __syncthreads();
    int gid = blockIdx.x * 256 + tid;
    int f = gid >> 2, sub = gid & 3;
    float4 h = *(const float4*)(ps + (size_t)f * 16 + sub * 4);
    if (MODE == 0) {
        *(float4*)(seqf + (size_t)f * 9 * 16 + sub * 4) = h;
    } else if (MODE == 1) {
        ushort4 u4;
        u4.x = f2bf(h.x); u4.y = f2bf(h.y); u4.z = f2bf(h.z); u4.w = f2bf(h.w);
        *(ushort4*)(seqb + (size_t)f * 16 + sub * 4) = u4;  // row 0
    }
    float4 bz = *(const float4*)(sbg + sub * 4);
    float4 br = *(const float4*)(sbg + 16 + sub * 4);
    float4 bc = *(const float4*)(sbg + 32 + sub * 4);
    for (int t = 0; t < 8; ++t) {
        int lk = ltp[(size_t)f * 8 + t];
        const float* xb = xk + (size_t)lk * XKS + sub * 4;
        float4 za = *(const float4*)xb;
        float4 ra = *(const float4*)(xb + 16);
        float4 ca = *(const float4*)(xb + 32);
        za.x += bz.x; za.y += bz.y; za.z += bz.z; za.w += bz.w;
        ra.x += br.x; ra.y += br.y; ra.z += br.z; ra.w += br.w;
        float4 cg = bc;
#pragma unroll
        for (int i = 0; i < 16; ++i) {
            float hsrc = ((i & 3) == 0) ? h.x : ((i & 3) == 1) ? h.y
                       : ((i & 3) == 2) ? h.z : h.w;
            float hi = __shfl(hsrc, i >> 2, 4);
            const float* w = srk + i * 48 + sub * 4;
            float4 wz = *(const float4*)w;
            float4 wr = *(const float4*)(w + 16);
            float4 wc = *(const float4*)(w + 32);
            za.x += hi * wz.x; za.y += hi * wz.y; za.z += hi * wz.z; za.w += hi * wz.w;
            ra.x += hi * wr.x; ra.y += hi * wr.y; ra.z += hi * wr.z; ra.w += hi * wr.w;
            cg.x += hi * wc.x; cg.y += hi * wc.y; cg.z += hi * wc.z; cg.w += hi * wc.w;
        }
        {
            float z = sigm(za.x), r = sigm(ra.x);
            float c = tanhfast(ca.x + r * cg.x);
            h.x = z * h.x + (1.0f - z) * c;
            z = sigm(za.y); r = sigm(ra.y);
            c = tanhfast(ca.y + r * cg.y);
            h.y = z * h.y + (1.0f - z) * c;
            z = sigm(za.z); r = sigm(ra.z);
            c = tanhfast(ca.z + r * cg.z);
            h.z = z * h.z + (1.0f - z) * c;
            z = sigm(za.w); r = sigm(ra.w);
            c = tanhfast(ca.w + r * cg.w);
            h.w = z * h.w + (1.0f - z) * c;
        }
        if (MODE == 0) {
            *(float4*)(seqf + ((size_t)f * 9 + t + 1) * 16 + sub * 4) = h;
        } else if (MODE == 1) {
            if (t < 7) {  // row 8 never gathered (p_pos < 8)
                ushort4 u4;
                u4.x = f2bf(h.x); u4.y = f2bf(h.y); u4.z = f2bf(h.z); u4.w = f2bf(h.w);
                *(ushort4*)(seqb + ((size_t)(t + 1) * NF + f) * 16 + sub * 4) = u4;
            }
        } else {
            *(float4*)(seqf + ((size_t)f * 8 + t) * 16 + sub * 4) = h;
        }
    }
    if (MODE != 2) *(float4*)(ps + (size_t)f * 16 + sub * 4) = h;
}

// ---------------- K2: attention message + link GRU (+ xk fold) ----------------
// Wave-level butterfly reduction (no LDS tree); parallel gate dot-products.
template <bool BF16>
__global__ __launch_bounds__(128) void k_link_upd(
    const void* __restrict__ seqv, const int* __restrict__ p2l,
    float* __restrict__ ls,
    const float* __restrict__ aw, const float* __restrict__ ab,
    const float* __restrict__ gk, const float* __restrict__ grk,
    const float* __restrict__ gb,
    float* __restrict__ xk, const float* __restrict__ pgk,
    const float* __restrict__ pgb) {
    __shared__ float sW[256], sB[16], cross[2][16], smsg[16], sh[16], sga[96];
    int tid = threadIdx.x;
    int link = blockIdx.x;
    sW[tid] = aw[tid];
    sW[tid + 128] = aw[tid + 128];
    if (tid < 16) { sB[tid] = ab[tid]; sh[tid] = ls[(size_t)link * 16 + tid]; }
    __syncthreads();
    int2 pp = ((const int2*)p2l)[(size_t)link * PPL + tid];
    float pg[16];
    if (BF16) {
        const unsigned short* sp =
            (const unsigned short*)seqv + ((size_t)pp.y * NF + pp.x) * 16;
        uint4 q0 = *(const uint4*)sp;
        uint4 q1 = *(const uint4*)(sp + 8);
        pg[0] = bflo(q0.x); pg[1] = bfhi(q0.x); pg[2] = bflo(q0.y); pg[3] = bfhi(q0.y);
        pg[4] = bflo(q0.z); pg[5] = bfhi(q0.z); pg[6] = bflo(q0.w); pg[7] = bfhi(q0.w);
        pg[8] = bflo(q1.x); pg[9] = bfhi(q1.x); pg[10] = bflo(q1.y); pg[11] = bfhi(q1.y);
        pg[12] = bflo(q1.z); pg[13] = bfhi(q1.z); pg[14] = bflo(q1.w); pg[15] = bfhi(q1.w);
    } else {
        const float4* pv =
            (const float4*)((const float*)seqv + ((size_t)pp.x * 9 + pp.y) * 16);
        float4* pr = (float4*)pg;
        pr[0] = pv[0]; pr[1] = pv[1]; pr[2] = pv[2]; pr[3] = pv[3];
    }
    float at[16];
#pragma unroll
    for (int u = 0; u < 16; ++u) {
        float a = sB[u];
#pragma unroll
        for (int i = 0; i < 16; ++i) a += pg[i] * sW[i * 16 + u];
        at[u] = a > 0.0f ? a : 0.01f * a;
    }
    float mx = at[0];
#pragma unroll
    for (int u = 1; u < 16; ++u) mx = fmaxf(mx, at[u]);
    float e[16];
    float ssum = 0.0f;
#pragma unroll
    for (int u = 0; u < 16; ++u) { e[u] = __expf(at[u] - mx); ssum += e[u]; }
    float inv = 1.0f / ssum;
    float w[16];
#pragma unroll
    for (int u = 0; u < 16; ++u) w[u] = e[u] * inv * pg[u];
    // butterfly reduce across the 64-lane wave
#pragma unroll
    for (int off = 1; off < 64; off <<= 1) {
#pragma unroll
        for (int u = 0; u < 16; ++u) w[u] += __shfl_xor(w[u], off);
    }
    int wid = tid >> 6, lane = tid & 63;
    if (lane < 16) cross[wid][lane] = w[lane];
    __syncthreads();
    if (tid < 16) smsg[tid] = cross[0][tid] + cross[1][tid];
    __syncthreads();
    // parallel gates: tid<96: side 0 = msg@gk + gb[0], side 1 = h@grk + gb[1]
    if (tid < 96) {
        int side = tid / 48;
        int col = tid - side * 48;
        const float* W = side ? grk : gk;
        const float* vin = side ? sh : smsg;
        float a = gb[side * 48 + col];
#pragma unroll
        for (int i = 0; i < 16; ++i) a += vin[i] * W[i * 48 + col];
        sga[tid] = a;
    }
    __syncthreads();
    if (tid < 16) {
        float z = sigm(sga[tid] + sga[48 + tid]);
        float r = sigm(sga[16 + tid] + sga[64 + tid]);
        float c = tanhfast(sga[32 + tid] + r * sga[80 + tid]);
        float hn = z * sh[tid] + (1.0f - z) * c;
        ls[(size_t)link * 16 + tid] = hn;
        sh[tid] = hn;
    }
    __syncthreads();
    if (tid < 48) {
        float a = pgb[tid];
#pragma unroll
        for (int i = 0; i < 16; ++i) a += sh[i] * pgk[i * 48 + tid];
        xk[(size_t)link * XKS + tid] = a;
    }
}

// ---------------- K4: KAN readout (sparse 4-basis spline) ----------------
template <int M>
__global__ __launch_bounds__(256) void k_kan(
    const float* __restrict__ seqf, const int* __restrict__ ltp,
    const float* __restrict__ cap,
    const float* __restrict__ sp1, const float* __restrict__ ba1,
    const float* __restrict__ bi1,
    const float* __restrict__ sp2, const float* __restrict__ ba2,
    const float* __restrict__ bi2,
    float* __restrict__ out) {
    // padded spline tables: rows r = jj+3, jj in [0,8) real, else 0
    __shared__ float s1p[16 * 14 * 16];  // [i][r][u]
    __shared__ float s2p[16 * 14];       // [i][r]
    __shared__ float sba1[256], sbi1[16], sba2[16];
    int tid = threadIdx.x;
    for (int k = tid; k < 16 * 14 * 16; k += 256) {
        int u = k & 15;
        int r = (k >> 4) % 14;
        int i = k / (14 * 16);
        int jj = r - 3;
        s1p[k] = (jj >= 0 && jj < 8) ? sp1[(i * 8 + jj) * 16 + u] : 0.0f;
    }
    for (int k = tid; k < 16 * 14; k += 256) {
        int r = k % 14;
        int i = k / 14;
        int jj = r - 3;
        s2p[k] = (jj >= 0 && jj < 8) ? sp2[i * 8 + jj] : 0.0f;
    }
    sba1[tid] = ba1[tid];
    if (tid < 16) { sbi1[tid] = bi1[tid]; sba2[tid] = ba2[tid]; }
    __syncthreads();
    int gt = blockIdx.x * 256 + tid;
    int f = gt >> 3, t = gt & 7;
    float x[16];
    {
        const float4* xv = (M == 0)
            ? (const float4*)(seqf + ((size_t)f * 9 + 1 + t) * 16)
            : (const float4*)(seqf + ((size_t)f * 8 + t) * 16);
        float4* xr = (float4*)x;
        xr[0] = xv[0]; xr[1] = xv[1]; xr[2] = xv[2]; xr[3] = xv[3];
    }
    float hh[16];
#pragma unroll
    for (int u = 0; u < 16; ++u) hh[u] = sbi1[u];
#pragma unroll
    for (int i = 0; i < 16; ++i) {
        float B0, B1, B2, B3;
        int idx = bspline4(x[i], B0, B1, B2, B3);
        const float* row = s1p + (i * 14 + idx) * 16;
#pragma unroll
        for (int u = 0; u < 16; ++u)
            hh[u] += B0 * row[u] + B1 * row[16 + u] + B2 * row[32 + u] + B3 * row[48 + u];
        float sil = x[i] * sigm(x[i]);
#pragma unroll
        for (int u = 0; u < 16; ++u) hh[u] += sil * sba1[i * 16 + u];
    }
    float occ = bi2[0];
#pragma unroll
    for (int i = 0; i < 16; ++i) {
        float B0, B1, B2, B3;
        int idx = bspline4(hh[i], B0, B1, B2, B3);
        const float* rw = s2p + i * 14 + idx;
        occ += B0 * rw[0] + B1 * rw[1] + B2 * rw[2] + B3 * rw[3];
        occ += hh[i] * sigm(hh[i]) * sba2[i];
    }
    int lk = ltp[(size_t)f * 8 + t];
    float val = occ / cap[lk];
#pragma unroll
    for (int off = 4; off; off >>= 1) val += __shfl_xor(val, off, 8);
    if (t == 0) out[f] = val;
}

extern "C" void kernel_launch(void* const* d_in, const int* in_sizes, int n_in,
                              void* d_out, int out_size, void* d_ws, size_t ws_size,
                              hipStream_t stream) {
    const float* f_tr   = (const float*)d_in[0];
    const float* f_pk   = (const float*)d_in[1];
    const float* f_ppb  = (const float*)d_in[2];
    const float* f_bpb  = (const float*)d_in[3];
    const float* f_psz  = (const float*)d_in[4];
    const float* f_p90  = (const float*)d_in[5];
    const float* f_rate = (const float*)d_in[6];
    const float* f_ipgm = (const float*)d_in[7];
    const float* f_ibg  = (const float*)d_in[8];
    const float* f_ipgv = (const float*)d_in[9];
    const float* f_type = (const float*)d_in[10];
    const float* f_cap  = (const float*)d_in[11];
    const float* f_mll  = (const float*)d_in[12];
    const int*   i_flen = (const int*)d_in[13];
    const int*   i_ltp  = (const int*)d_in[15];
    const int*   i_p2l  = (const int*)d_in[16];
    const float* fe_w1 = (const float*)d_in[17];
    const float* fe_b1 = (const float*)d_in[18];
    const float* fe_w2 = (const float*)d_in[19];
    const float* fe_b2 = (const float*)d_in[20];
    const float* le_w1 = (const float*)d_in[21];
    const float* le_b1 = (const float*)d_in[22];
    const float* le_w2 = (const float*)d_in[23];
    const float* le_b2 = (const float*)d_in[24];
    const float* at_w  = (const float*)d_in[25];
    const float* at_b  = (const float*)d_in[26];
    const float* pg_k  = (const float*)d_in[27];
    const float* pg_rk = (const float*)d_in[28];
    const float* pg_b  = (const float*)d_in[29];
    const float* lg_k  = (const float*)d_in[30];
    const float* lg_rk = (const float*)d_in[31];
    const float* lg_b  = (const float*)d_in[32];
    const float* k1_sp = (const float*)d_in[33];
    const float* k1_ba = (const float*)d_in[34];
    const float* k1_bi = (const float*)d_in[35];
    const float* k2_sp = (const float*)d_in[36];
    const float* k2_ba = (const float*)d_in[37];
    const float* k2_bi = (const float*)d_in[38];

    float* ws = (float*)d_ws;
    float* ps   = ws;
    float* ls   = ps + (size_t)NF * 16;
    float* xk   = ls + (size_t)NL * 16;
    float* load = xk + (size_t)NL * XKS;
    float* tail = load + NL;
    size_t head_bytes = (size_t)(tail - ws) * 4;
    unsigned short* seqb = (unsigned short*)tail;          // bf16 [8][NF][16]
    size_t seqb_elems = (size_t)NF * 8 * 16;
    float* seqfL = (float*)(seqb + seqb_elems);            // f32 [NF][8][16]
    size_t need_bf = head_bytes + seqb_elems * 2 + (size_t)NF * 8 * 16 * 4;
    float* seq32 = tail;                                   // fallback f32 [NF][9][16]
    bool bfp = ws_size >= need_bf;
    float* out = (float*)d_out;

    k_load<<<NL * 64 / 256, 256, 0, stream>>>(i_p2l, f_tr, f_cap, load);
    k_flow_enc<<<NF / 256, 256, 0, stream>>>(f_tr, f_pk, f_ppb, f_bpb, f_psz, f_p90,
                                             f_rate, f_ipgm, f_ibg, f_ipgv, f_type,
                                             i_flen, fe_w1, fe_b1, fe_w2, fe_b2, ps);
    k_link_enc<<<NL / 256, 256, 0, stream>>>(f_cap, load, f_mll, le_w1, le_b1, le_w2,
                                             le_b2, ls, xk, pg_k, pg_b);
    if (bfp) {
        for (int it = 0; it < 12; ++it) {
            if (it < 11) {
                k_path4<1><<<NF * 4 / 256, 256, 0, stream>>>(xk, i_ltp, ps, seqb,
                                                             nullptr, pg_rk, pg_b);
                k_link_upd<true><<<NL, 128, 0, stream>>>(seqb, i_p2l, ls, at_w, at_b,
                                                         lg_k, lg_rk, lg_b, xk, pg_k, pg_b);
            } else {
                k_path4<2><<<NF * 4 / 256, 256, 0, stream>>>(xk, i_ltp, ps, nullptr,
                                                             seqfL, pg_rk, pg_b);
            }
        }
        k_kan<1><<<NF * 8 / 256, 256, 0, stream>>>(seqfL, i_ltp, f_cap, k1_sp, k1_ba,
                                                   k1_bi, k2_sp, k2_ba, k2_bi, out);
    } else {
        for (int it = 0; it < 12; ++it) {
            k_path4<0><<<NF * 4 / 256, 256, 0, stream>>>(xk, i_ltp, ps, nullptr,
                                                         seq32, pg_rk, pg_b);
            if (it < 11)
                k_link_upd<false><<<NL, 128, 0, stream>>>(seq32, i_p2l, ls, at_w, at_b,
                                                          lg_k, lg_rk, lg_b, xk, pg_k, pg_b);
        }
        k_kan<0><<<NF * 8 / 256, 256, 0, stream>>>(seq32, i_ltp, f_cap, k1_sp, k1_ba,
                                                   k1_bi, k2_sp, k2_ba, k2_bi, out);
    }
}

// Round 5
// 850.277 us; speedup vs baseline: 1.1315x; 1.1315x over previous
//
#include <hip/hip_runtime.h>
#include <cstdint>

#define NF 65536
#define PL 8
#define NL 4096
#define PPL 128
#define XKS 64  // padded xk record stride (floats): 256 B, cacheline-aligned

__device__ __forceinline__ float sigm(float v) { return 1.0f / (1.0f + __expf(-v)); }
__device__ __forceinline__ float tanhfast(float v) {
    float e = __expf(2.0f * v);
    return 1.0f - 2.0f / (e + 1.0f);
}
__device__ __forceinline__ float seluf(float x) {
    return x > 0.0f ? 1.0507009873554805f * x : 1.7580993408473766f * (__expf(x) - 1.0f);
}
__device__ __forceinline__ unsigned short f2bf(float x) {
    unsigned u = __float_as_uint(x);
    u += 0x7fffu + ((u >> 16) & 1u);
    return (unsigned short)(u >> 16);
}
__device__ __forceinline__ float bflo(unsigned u) { return __uint_as_float(u << 16); }
__device__ __forceinline__ float bfhi(unsigned u) { return __uint_as_float(u & 0xffff0000u); }

// permuted xk/gate column: gate g, dim d -> (d>>1)*6 + g*2 + (d&1)
__device__ __forceinline__ int gcol(int g, int d) {
    return (d >> 1) * 6 + g * 2 + (d & 1);
}

// Sparse cubic B-spline: 4 active bases at local u, interval idx. Uniform knots
// t_j = (j-3)*0.4 - 1 (identical to jnp _knots pyramid; closed-form is exact).
__device__ __forceinline__ int bspline4(float xx, float& B0, float& B1, float& B2,
                                        float& B3) {
    const float KN0 = (0 - 3) * 0.4f - 1.0f;    // t_0  = -2.2
    float s = (xx - KN0) * 2.5f;
    int idx = (int)floorf(s);
    bool valid = (idx >= 0) && (idx <= 10);     // outside [t_0, t_11): all bases 0
    idx = min(max(idx, 0), 10);
    float tI = (float)(idx - 3) * 0.4f - 1.0f;
    float u = (xx - tI) * 2.5f;
    float um = 1.0f - u;
    float u2 = u * u, u3 = u2 * u;
    B0 = um * um * um * (1.0f / 6.0f);
    B1 = 0.5f * u3 - u2 + (2.0f / 3.0f);
    B2 = -0.5f * u3 + 0.5f * u2 + 0.5f * u + (1.0f / 6.0f);
    B3 = u3 * (1.0f / 6.0f);
    if (!valid) { B0 = 0.f; B1 = 0.f; B2 = 0.f; B3 = 0.f; }
    return idx;
}

// ---------------- S1: per-link load ----------------
__global__ __launch_bounds__(256) void k_load(const int* __restrict__ p2l,
                                              const float* __restrict__ ft,
                                              const float* __restrict__ cap,
                                              float* __restrict__ load) {
    int gid = blockIdx.x * 256 + threadIdx.x;
    int link = gid >> 6;
    int lane = threadIdx.x & 63;
    const int2* b2 = (const int2*)(p2l + (size_t)link * PPL * 2);
    int2 v0 = b2[lane];
    int2 v1 = b2[lane + 64];
    float s = ft[v0.x] + ft[v1.x];
#pragma unroll
    for (int off = 32; off; off >>= 1) s += __shfl_xor(s, off);
    if (lane == 0) load[link] = s / (cap[link] * 1e9f);
}

// ---------------- S2: flow encoder -> path_state ----------------
__global__ __launch_bounds__(256) void k_flow_enc(
    const float* __restrict__ tr, const float* __restrict__ pk,
    const float* __restrict__ ppb, const float* __restrict__ bpb,
    const float* __restrict__ psz, const float* __restrict__ p90,
    const float* __restrict__ rate, const float* __restrict__ ipgm,
    const float* __restrict__ ibg, const float* __restrict__ ipgv,
    const float* __restrict__ ftype, const int* __restrict__ flen,
    const float* __restrict__ w1, const float* __restrict__ b1,
    const float* __restrict__ w2, const float* __restrict__ b2,
    float* __restrict__ ps) {
    __shared__ float sw1[13 * 16], sb1[16], sw2[256], sb2[16];
    int tid = threadIdx.x;
    if (tid < 208) sw1[tid] = w1[tid];
    sw2[tid] = w2[tid];
    if (tid < 16) { sb1[tid] = b1[tid]; sb2[tid] = b2[tid]; }
    __syncthreads();
    int f = blockIdx.x * 256 + tid;
    float feat[13];
    feat[0] = (tr[f] - 0.5f) * 2.0f;
    feat[1] = (pk[f] - 0.5f) * 2.0f;
    feat[2] = (ibg[f] - 0.5f) * 2.0f;
    feat[3] = (rate[f] - 0.5f) * 2.0f;
    feat[4] = (p90[f] - 0.5f) * 2.0f;
    feat[5] = (psz[f] - 0.5f) * 2.0f;
    feat[6] = (bpb[f] - 0.5f) * 2.0f;
    feat[7] = (ipgm[f] - 0.5f) * 2.0f;
    feat[8] = (ipgv[f] - 0.5f) * 2.0f;
    feat[9] = (ppb[f] - 0.5f) * 2.0f;
    feat[10] = (float)flen[f];
    float2 ft2 = ((const float2*)ftype)[f];
    feat[11] = ft2.x;
    feat[12] = ft2.y;
    float t1[16];
#pragma unroll
    for (int u = 0; u < 16; ++u) {
        float a = sb1[u];
#pragma unroll
        for (int i = 0; i < 13; ++i) a += feat[i] * sw1[i * 16 + u];
        t1[u] = seluf(a);
    }
    float out[16];
#pragma unroll
    for (int u = 0; u < 16; ++u) {
        float a = sb2[u];
#pragma unroll
        for (int i = 0; i < 16; ++i) a += t1[i] * sw2[i * 16 + u];
        out[u] = seluf(a);
    }
    float4* o4 = (float4*)(ps + (size_t)f * 16);
    const float4* s4 = (const float4*)out;
#pragma unroll
    for (int q = 0; q < 4; ++q) o4[q] = s4[q];
}

// ---------------- S3: link encoder -> link_state (+ xk fold, permuted) ----------------
__global__ __launch_bounds__(256) void k_link_enc(
    const float* __restrict__ cap, const float* __restrict__ load,
    const float* __restrict__ mll,
    const float* __restrict__ w1, const float* __restrict__ b1,
    const float* __restrict__ w2, const float* __restrict__ b2,
    float* __restrict__ ls, float* __restrict__ xk,
    const float* __restrict__ pgk, const float* __restrict__ pgb) {
    int l = blockIdx.x * 256 + threadIdx.x;
    if (l >= NL) return;
    float f0 = (cap[l] - 5.0f) * 0.25f;
    float f1 = load[l];
    float f2 = f1 / mll[0];
    float f3 = 8.0f / 32768.0f;
    float t1[16];
#pragma unroll
    for (int u = 0; u < 16; ++u) {
        float a = b1[u] + f0 * w1[u] + f1 * w1[16 + u] + f2 * w1[32 + u] + f3 * w1[48 + u];
        t1[u] = seluf(a);
    }
    float out[16];
#pragma unroll
    for (int u = 0; u < 16; ++u) {
        float a = b2[u];
#pragma unroll
        for (int i = 0; i < 16; ++i) a += t1[i] * w2[i * 16 + u];
        out[u] = seluf(a);
    }
    float4* o4 = (float4*)(ls + (size_t)l * 16);
    const float4* s4 = (const float4*)out;
#pragma unroll
    for (int q = 0; q < 4; ++q) o4[q] = s4[q];
    for (int u = 0; u < 48; ++u) {  // u = old col = g*16 + d
        float a = pgb[u];
#pragma unroll
        for (int i = 0; i < 16; ++i) a += out[i] * pgk[i * 48 + u];
        int g = u >> 4, d = u & 15;
        xk[(size_t)l * XKS + gcol(g, d)] = a;
    }
}

// ---------------- K1: path GRU, 8 threads/flow, weights in registers ----------------
// Thread sub owns dims d0=2*sub, d1=2*sub+1 across all gates (thread-local gate math).
// MODE 0: f32 seq [f][9][16] rows 0..8; MODE 1: bf16 seq [t][NF][16] rows 0..7;
// MODE 2: f32 seqF [f][8][16] rows 1..8 (KAN input)
template <int MODE>
__global__ __launch_bounds__(256) void k_path8(
    const float* __restrict__ xk, const int* __restrict__ ltp,
    float* __restrict__ ps, unsigned short* __restrict__ seqb,
    float* __restrict__ seqf,
    const float* __restrict__ grk, const float* __restrict__ gb) {
    __shared__ float srk[768], sbg[48];
    int tid = threadIdx.x;
    for (int i = tid; i < 768; i += 256) srk[i] = grk[i];
    if (tid < 48) sbg[tid] = gb[48 + tid];
    __syncthreads();
    int gid = blockIdx.x * 256 + tid;
    int f = gid >> 3, sub = gid & 7;
    // per-thread weight slices: wz/wr/wc[i] = grk[i][gate][d0..d1]
    float2 wz[16], wr[16], wc[16];
#pragma unroll
    for (int i = 0; i < 16; ++i) {
        wz[i] = *(const float2*)(srk + i * 48 + sub * 2);
        wr[i] = *(const float2*)(srk + i * 48 + 16 + sub * 2);
        wc[i] = *(const float2*)(srk + i * 48 + 32 + sub * 2);
    }
    float2 bgz = *(const float2*)(sbg + sub * 2);
    float2 bgr = *(const float2*)(sbg + 16 + sub * 2);
    float2 bgc = *(const float2*)(sbg + 32 + sub * 2);
    float2 h = *(const float2*)(ps + (size_t)f * 16 + sub * 2);
    if (MODE == 0) {
        *(float2*)(seqf + (size_t)f * 9 * 16 + sub * 2) = h;
    } else if (MODE == 1) {
        ushort2 u2;
        u2.x = f2bf(h.x); u2.y = f2bf(h.y);
        *(ushort2*)(seqb + (size_t)f * 16 + sub * 2) = u2;  // row 0
    }
    for (int t = 0; t < 8; ++t) {
        int lk = ltp[(size_t)f * 8 + t];
        const float* xb = xk + (size_t)lk * XKS + sub * 6;
        float2 za = *(const float2*)xb;        // x-side z (incl x-bias)
        float2 ra = *(const float2*)(xb + 2);  // x-side r
        float2 ca = *(const float2*)(xb + 4);  // x-side c (kept separate)
        za.x += bgz.x; za.y += bgz.y;
        ra.x += bgr.x; ra.y += bgr.y;
        float2 cg = bgc;                       // h-side c accumulator
#pragma unroll
        for (int j = 0; j < 8; ++j) {
            float hA = __shfl(h.x, j, 8);      // h[2j]
            float hB = __shfl(h.y, j, 8);      // h[2j+1]
            int i0 = 2 * j, i1 = 2 * j + 1;
            za.x += hA * wz[i0].x; za.y += hA * wz[i0].y;
            ra.x += hA * wr[i0].x; ra.y += hA * wr[i0].y;
            cg.x += hA * wc[i0].x; cg.y += hA * wc[i0].y;
            za.x += hB * wz[i1].x; za.y += hB * wz[i1].y;
            ra.x += hB * wr[i1].x; ra.y += hB * wr[i1].y;
            cg.x += hB * wc[i1].x; cg.y += hB * wc[i1].y;
        }
        {
            float z = sigm(za.x), r = sigm(ra.x);
            float c = tanhfast(ca.x + r * cg.x);
            h.x = z * h.x + (1.0f - z) * c;
            z = sigm(za.y); r = sigm(ra.y);
            c = tanhfast(ca.y + r * cg.y);
            h.y = z * h.y + (1.0f - z) * c;
        }
        if (MODE == 0) {
            *(float2*)(seqf + ((size_t)f * 9 + t + 1) * 16 + sub * 2) = h;
        } else if (MODE == 1) {
            if (t < 7) {  // row 8 never gathered (p_pos < 8)
                ushort2 u2;
                u2.x = f2bf(h.x); u2.y = f2bf(h.y);
                *(ushort2*)(seqb + ((size_t)(t + 1) * NF + f) * 16 + sub * 2) = u2;
            }
        } else {
            *(float2*)(seqf + ((size_t)f * 8 + t) * 16 + sub * 2) = h;
        }
    }
    if (MODE != 2) *(float2*)(ps + (size_t)f * 16 + sub * 2) = h;
}

// ---------------- K2: attention message + link GRU (+ permuted xk fold) ----------------
// Round-3 proven structure: LDS-tree reduction, serial-16 GRU tail.
template <bool BF16>
__global__ __launch_bounds__(128) void k_link_upd(
    const void* __restrict__ seqv, const int* __restrict__ p2l,
    float* __restrict__ ls,
    const float* __restrict__ aw, const float* __restrict__ ab,
    const float* __restrict__ gk, const float* __restrict__ grk,
    const float* __restrict__ gb,
    float* __restrict__ xk, const float* __restrict__ pgk,
    const float* __restrict__ pgb) {
    __shared__ float sW[256], sB[16], red[128][17], sh[16], sh2[16];
    int tid = threadIdx.x;
    int link = blockIdx.x;
    sW[tid] = aw[tid];
    sW[tid + 128] = aw[tid + 128];
    if (tid < 16) sB[tid] = ab[tid];
    __syncthreads();
    int2 pp = ((const int2*)p2l)[(size_t)link * PPL + tid];
    float pg[16];
    if (BF16) {
        const unsigned short* sp =
            (const unsigned short*)seqv + ((size_t)pp.y * NF + pp.x) * 16;
        uint4 q0 = *(const uint4*)sp;
        uint4 q1 = *(const uint4*)(sp + 8);
        pg[0] = bflo(q0.x); pg[1] = bfhi(q0.x); pg[2] = bflo(q0.y); pg[3] = bfhi(q0.y);
        pg[4] = bflo(q0.z); pg[5] = bfhi(q0.z); pg[6] = bflo(q0.w); pg[7] = bfhi(q0.w);
        pg[8] = bflo(q1.x); pg[9] = bfhi(q1.x); pg[10] = bflo(q1.y); pg[11] = bfhi(q1.y);
        pg[12] = bflo(q1.z); pg[13] = bfhi(q1.z); pg[14] = bflo(q1.w); pg[15] = bfhi(q1.w);
    } else {
        const float4* pv =
            (const float4*)((const float*)seqv + ((size_t)pp.x * 9 + pp.y) * 16);
        float4* pr = (float4*)pg;
        pr[0] = pv[0]; pr[1] = pv[1]; pr[2] = pv[2]; pr[3] = pv[3];
    }
    float at[16];
#pragma unroll
    for (int u = 0; u < 16; ++u) {
        float a = sB[u];
#pragma unroll
        for (int i = 0; i < 16; ++i) a += pg[i] * sW[i * 16 + u];
        at[u] = a > 0.0f ? a : 0.01f * a;
    }
    float mx = at[0];
#pragma unroll
    for (int u = 1; u < 16; ++u) mx = fmaxf(mx, at[u]);
    float e[16];
    float ssum = 0.0f;
#pragma unroll
    for (int u = 0; u < 16; ++u) { e[u] = __expf(at[u] - mx); ssum += e[u]; }
    float inv = 1.0f / ssum;
#pragma unroll
    for (int u = 0; u < 16; ++u) red[tid][u] = e[u] * inv * pg[u];
    __syncthreads();
    for (int s = 64; s > 0; s >>= 1) {
        if (tid < s) {
#pragma unroll
            for (int u = 0; u < 16; ++u) red[tid][u] += red[tid + s][u];
        }
        __syncthreads();
    }
    if (tid < 16) sh[tid] = ls[(size_t)link * 16 + tid];
    __syncthreads();
    if (tid < 16) {
        int d = tid;
        float az = gb[d], ar = gb[16 + d], ac = gb[32 + d];
        float gz = gb[48 + d], gr = gb[64 + d], gc = gb[80 + d];
#pragma unroll
        for (int i = 0; i < 16; ++i) {
            float mi = red[0][i];
            float hi = sh[i];
            az += mi * gk[i * 48 + d];
            ar += mi * gk[i * 48 + 16 + d];
            ac += mi * gk[i * 48 + 32 + d];
            gz += hi * grk[i * 48 + d];
            gr += hi * grk[i * 48 + 16 + d];
            gc += hi * grk[i * 48 + 32 + d];
        }
        float z = sigm(az + gz);
        float r = sigm(ar + gr);
        float c = tanhfast(ac + r * gc);
        float hn = z * sh[d] + (1.0f - z) * c;
        ls[(size_t)link * 16 + d] = hn;
        sh2[d] = hn;
    }
    __syncthreads();
    if (tid < 48) {  // tid = old col = g*16 + d
        float a = pgb[tid];
#pragma unroll
        for (int i = 0; i < 16; ++i) a += sh2[i] * pgk[i * 48 + tid];
        int g = tid >> 4, d = tid & 15;
        xk[(size_t)link * XKS + gcol(g, d)] = a;
    }
}

// ---------------- K4: KAN readout (sparse 4-basis spline) ----------------
template <int M>
__global__ __launch_bounds__(256) void k_kan(
    const float* __restrict__ seqf, const int* __restrict__ ltp,
    const float* __restrict__ cap,
    const float* __restrict__ sp1, const float* __restrict__ ba1,
    const float* __restrict__ bi1,
    const float* __restrict__ sp2, const float* __restrict__ ba2,
    const float* __restrict__ bi2,
    float* __restrict__ out) {
    // padded spline tables: rows r = jj+3, jj in [0,8) real, else 0
    __shared__ float s1p[16 * 14 * 16];  // [i][r][u]
    __shared__ float s2p[16 * 14];       // [i][r]
    __shared__ float sba1[256], sbi1[16], sba2[16];
    int tid = threadIdx.x;
    for (int k = tid; k < 16 * 14 * 16; k += 256) {
        int u = k & 15;
        int r = (k >> 4) % 14;
        int i = k / (14 * 16);
        int jj = r - 3;
        s1p[k] = (jj >= 0 && jj < 8) ? sp1[(i * 8 + jj) * 16 + u] : 0.0f;
    }
    for (int k = tid; k < 16 * 14; k += 256) {
        int r = k % 14;
        int i = k / 14;
        int jj = r - 3;
        s2p[k] = (jj >= 0 && jj < 8) ? sp2[i * 8 + jj] : 0.0f;
    }
    sba1[tid] = ba1[tid];
    if (tid < 16) { sbi1[tid] = bi1[tid]; sba2[tid] = ba2[tid]; }
    __syncthreads();
    int gt = blockIdx.x * 256 + tid;
    int f = gt >> 3, t = gt & 7;
    float x[16];
    {
        const float4* xv = (M == 0)
            ? (const float4*)(seqf + ((size_t)f * 9 + 1 + t) * 16)
            : (const float4*)(seqf + ((size_t)f * 8 + t) * 16);
        float4* xr = (float4*)x;
        xr[0] = xv[0]; xr[1] = xv[1]; xr[2] = xv[2]; xr[3] = xv[3];
    }
    float hh[16];
#pragma unroll
    for (int u = 0; u < 16; ++u) hh[u] = sbi1[u];
#pragma unroll
    for (int i = 0; i < 16; ++i) {
        float B0, B1, B2, B3;
        int idx = bspline4(x[i], B0, B1, B2, B3);
        const float* row = s1p + (i * 14 + idx) * 16;
#pragma unroll
        for (int u = 0; u < 16; ++u)
            hh[u] += B0 * row[u] + B1 * row[16 + u] + B2 * row[32 + u] + B3 * row[48 + u];
        float sil = x[i] * sigm(x[i]);
#pragma unroll
        for (int u = 0; u < 16; ++u) hh[u] += sil * sba1[i * 16 + u];
    }
    float occ = bi2[0];
#pragma unroll
    for (int i = 0; i < 16; ++i) {
        float B0, B1, B2, B3;
        int idx = bspline4(hh[i], B0, B1, B2, B3);
        const float* rw = s2p + i * 14 + idx;
        occ += B0 * rw[0] + B1 * rw[1] + B2 * rw[2] + B3 * rw[3];
        occ += hh[i] * sigm(hh[i]) * sba2[i];
    }
    int lk = ltp[(size_t)f * 8 + t];
    float val = occ / cap[lk];
#pragma unroll
    for (int off = 4; off; off >>= 1) val += __shfl_xor(val, off, 8);
    if (t == 0) out[f] = val;
}

extern "C" void kernel_launch(void* const* d_in, const int* in_sizes, int n_in,
                              void* d_out, int out_size, void* d_ws, size_t ws_size,
                              hipStream_t stream) {
    const float* f_tr   = (const float*)d_in[0];
    const float* f_pk   = (const float*)d_in[1];
    const float* f_ppb  = (const float*)d_in[2];
    const float* f_bpb  = (const float*)d_in[3];
    const float* f_psz  = (const float*)d_in[4];
    const float* f_p90  = (const float*)d_in[5];
    const float* f_rate = (const float*)d_in[6];
    const float* f_ipgm = (const float*)d_in[7];
    const float* f_ibg  = (const float*)d_in[8];
    const float* f_ipgv = (const float*)d_in[9];
    const float* f_type = (const float*)d_in[10];
    const float* f_cap  = (const float*)d_in[11];
    const float* f_mll  = (const float*)d_in[12];
    const int*   i_flen = (const int*)d_in[13];
    const int*   i_ltp  = (const int*)d_in[15];
    const int*   i_p2l  = (const int*)d_in[16];
    const float* fe_w1 = (const float*)d_in[17];
    const float* fe_b1 = (const float*)d_in[18];
    const float* fe_w2 = (const float*)d_in[19];
    const float* fe_b2 = (const float*)d_in[20];
    const float* le_w1 = (const float*)d_in[21];
    const float* le_b1 = (const float*)d_in[22];
    const float* le_w2 = (const float*)d_in[23];
    const float* le_b2 = (const float*)d_in[24];
    const float* at_w  = (const float*)d_in[25];
    const float* at_b  = (const float*)d_in[26];
    const float* pg_k  = (const float*)d_in[27];
    const float* pg_rk = (const float*)d_in[28];
    const float* pg_b  = (const float*)d_in[29];
    const float* lg_k  = (const float*)d_in[30];
    const float* lg_rk = (const float*)d_in[31];
    const float* lg_b  = (const float*)d_in[32];
    const float* k1_sp = (const float*)d_in[33];
    const float* k1_ba = (const float*)d_in[34];
    const float* k1_bi = (const float*)d_in[35];
    const float* k2_sp = (const float*)d_in[36];
    const float* k2_ba = (const float*)d_in[37];
    const float* k2_bi = (const float*)d_in[38];

    float* ws = (float*)d_ws;
    float* ps   = ws;
    float* ls   = ps + (size_t)NF * 16;
    float* xk   = ls + (size_t)NL * 16;
    float* load = xk + (size_t)NL * XKS;
    float* tail = load + NL;
    size_t head_bytes = (size_t)(tail - ws) * 4;
    unsigned short* seqb = (unsigned short*)tail;          // bf16 [8][NF][16]
    size_t seqb_elems = (size_t)NF * 8 * 16;
    float* seqfL = (float*)(seqb + seqb_elems);            // f32 [NF][8][16]
    size_t need_bf = head_bytes + seqb_elems * 2 + (size_t)NF * 8 * 16 * 4;
    float* seq32 = tail;                                   // fallback f32 [NF][9][16]
    bool bfp = ws_size >= need_bf;
    float* out = (float*)d_out;

    k_load<<<NL * 64 / 256, 256, 0, stream>>>(i_p2l, f_tr, f_cap, load);
    k_flow_enc<<<NF / 256, 256, 0, stream>>>(f_tr, f_pk, f_ppb, f_bpb, f_psz, f_p90,
                                             f_rate, f_ipgm, f_ibg, f_ipgv, f_type,
                                             i_flen, fe_w1, fe_b1, fe_w2, fe_b2, ps);
    k_link_enc<<<NL / 256, 256, 0, stream>>>(f_cap, load, f_mll, le_w1, le_b1, le_w2,
                                             le_b2, ls, xk, pg_k, pg_b);
    if (bfp) {
        for (int it = 0; it < 12; ++it) {
            if (it < 11) {
                k_path8<1><<<NF * 8 / 256, 256, 0, stream>>>(xk, i_ltp, ps, seqb,
                                                             nullptr, pg_rk, pg_b);
                k_link_upd<true><<<NL, 128, 0, stream>>>(seqb, i_p2l, ls, at_w, at_b,
                                                         lg_k, lg_rk, lg_b, xk, pg_k, pg_b);
            } else {
                k_path8<2><<<NF * 8 / 256, 256, 0, stream>>>(xk, i_ltp, ps, nullptr,
                                                             seqfL, pg_rk, pg_b);
            }
        }
        k_kan<1><<<NF * 8 / 256, 256, 0, stream>>>(seqfL, i_ltp, f_cap, k1_sp, k1_ba,
                                                   k1_bi, k2_sp, k2_ba, k2_bi, out);
    } else {
        for (int it = 0; it < 12; ++it) {
            k_path8<0><<<NF * 8 / 256, 256, 0, stream>>>(xk, i_ltp, ps, nullptr,
                                                         seq32, pg_rk, pg_b);
            if (it < 11)
                k_link_upd<false><<<NL, 128, 0, stream>>>(seq32, i_p2l, ls, at_w, at_b,
                                                          lg_k, lg_rk, lg_b, xk, pg_k, pg_b);
        }
        k_kan<0><<<NF * 8 / 256, 256, 0, stream>>>(seq32, i_ltp, f_cap, k1_sp, k1_ba,
                                                   k1_bi, k2_sp, k2_ba, k2_bi, out);
    }
}

// Round 6
// 692.861 us; speedup vs baseline: 1.3885x; 1.2272x over previous
//
#include <hip/hip_runtime.h>
#include <cstdint>

#define NF 65536
#define PL 8
#define NL 4096
#define PPL 128
#define XKS 64  // padded xk record stride (floats): 256 B, cacheline-aligned

typedef _Float16 f16x4 __attribute__((ext_vector_type(4)));
typedef float f32x4 __attribute__((ext_vector_type(4)));

__device__ __forceinline__ float sigm(float v) { return 1.0f / (1.0f + __expf(-v)); }
__device__ __forceinline__ float tanhfast(float v) {
    float e = __expf(2.0f * v);
    return 1.0f - 2.0f / (e + 1.0f);
}
__device__ __forceinline__ float seluf(float x) {
    return x > 0.0f ? 1.0507009873554805f * x : 1.7580993408473766f * (__expf(x) - 1.0f);
}
__device__ __forceinline__ unsigned short f2bf(float x) {
    unsigned u = __float_as_uint(x);
    u += 0x7fffu + ((u >> 16) & 1u);
    return (unsigned short)(u >> 16);
}
__device__ __forceinline__ float bflo(unsigned u) { return __uint_as_float(u << 16); }
__device__ __forceinline__ float bfhi(unsigned u) { return __uint_as_float(u & 0xffff0000u); }

// Sparse cubic B-spline: 4 active bases at local u, interval idx. Uniform knots
// t_j = (j-3)*0.4 - 1 (identical to jnp _knots pyramid; closed-form is exact).
__device__ __forceinline__ int bspline4(float xx, float& B0, float& B1, float& B2,
                                        float& B3) {
    const float KN0 = (0 - 3) * 0.4f - 1.0f;    // t_0  = -2.2
    float s = (xx - KN0) * 2.5f;
    int idx = (int)floorf(s);
    bool valid = (idx >= 0) && (idx <= 10);     // outside [t_0, t_11): all bases 0
    idx = min(max(idx, 0), 10);
    float tI = (float)(idx - 3) * 0.4f - 1.0f;
    float u = (xx - tI) * 2.5f;
    float um = 1.0f - u;
    float u2 = u * u, u3 = u2 * u;
    B0 = um * um * um * (1.0f / 6.0f);
    B1 = 0.5f * u3 - u2 + (2.0f / 3.0f);
    B2 = -0.5f * u3 + 0.5f * u2 + 0.5f * u + (1.0f / 6.0f);
    B3 = u3 * (1.0f / 6.0f);
    if (!valid) { B0 = 0.f; B1 = 0.f; B2 = 0.f; B3 = 0.f; }
    return idx;
}

// ---------------- S1: per-link load ----------------
__global__ __launch_bounds__(256) void k_load(const int* __restrict__ p2l,
                                              const float* __restrict__ ft,
                                              const float* __restrict__ cap,
                                              float* __restrict__ load) {
    int gid = blockIdx.x * 256 + threadIdx.x;
    int link = gid >> 6;
    int lane = threadIdx.x & 63;
    const int2* b2 = (const int2*)(p2l + (size_t)link * PPL * 2);
    int2 v0 = b2[lane];
    int2 v1 = b2[lane + 64];
    float s = ft[v0.x] + ft[v1.x];
#pragma unroll
    for (int off = 32; off; off >>= 1) s += __shfl_xor(s, off);
    if (lane == 0) load[link] = s / (cap[link] * 1e9f);
}

// ---------------- S2: flow encoder -> path_state ----------------
__global__ __launch_bounds__(256) void k_flow_enc(
    const float* __restrict__ tr, const float* __restrict__ pk,
    const float* __restrict__ ppb, const float* __restrict__ bpb,
    const float* __restrict__ psz, const float* __restrict__ p90,
    const float* __restrict__ rate, const float* __restrict__ ipgm,
    const float* __restrict__ ibg, const float* __restrict__ ipgv,
    const float* __restrict__ ftype, const int* __restrict__ flen,
    const float* __restrict__ w1, const float* __restrict__ b1,
    const float* __restrict__ w2, const float* __restrict__ b2,
    float* __restrict__ ps) {
    __shared__ float sw1[13 * 16], sb1[16], sw2[256], sb2[16];
    int tid = threadIdx.x;
    if (tid < 208) sw1[tid] = w1[tid];
    sw2[tid] = w2[tid];
    if (tid < 16) { sb1[tid] = b1[tid]; sb2[tid] = b2[tid]; }
    __syncthreads();
    int f = blockIdx.x * 256 + tid;
    float feat[13];
    feat[0] = (tr[f] - 0.5f) * 2.0f;
    feat[1] = (pk[f] - 0.5f) * 2.0f;
    feat[2] = (ibg[f] - 0.5f) * 2.0f;
    feat[3] = (rate[f] - 0.5f) * 2.0f;
    feat[4] = (p90[f] - 0.5f) * 2.0f;
    feat[5] = (psz[f] - 0.5f) * 2.0f;
    feat[6] = (bpb[f] - 0.5f) * 2.0f;
    feat[7] = (ipgm[f] - 0.5f) * 2.0f;
    feat[8] = (ipgv[f] - 0.5f) * 2.0f;
    feat[9] = (ppb[f] - 0.5f) * 2.0f;
    feat[10] = (float)flen[f];
    float2 ft2 = ((const float2*)ftype)[f];
    feat[11] = ft2.x;
    feat[12] = ft2.y;
    float t1[16];
#pragma unroll
    for (int u = 0; u < 16; ++u) {
        float a = sb1[u];
#pragma unroll
        for (int i = 0; i < 13; ++i) a += feat[i] * sw1[i * 16 + u];
        t1[u] = seluf(a);
    }
    float out[16];
#pragma unroll
    for (int u = 0; u < 16; ++u) {
        float a = sb2[u];
#pragma unroll
        for (int i = 0; i < 16; ++i) a += t1[i] * sw2[i * 16 + u];
        out[u] = seluf(a);
    }
    float4* o4 = (float4*)(ps + (size_t)f * 16);
    const float4* s4 = (const float4*)out;
#pragma unroll
    for (int q = 0; q < 4; ++q) o4[q] = s4[q];
}

// ---------------- S3: link encoder -> link_state (+ xk fold) ----------------
__global__ __launch_bounds__(256) void k_link_enc(
    const float* __restrict__ cap, const float* __restrict__ load,
    const float* __restrict__ mll,
    const float* __restrict__ w1, const float* __restrict__ b1,
    const float* __restrict__ w2, const float* __restrict__ b2,
    float* __restrict__ ls, float* __restrict__ xk,
    const float* __restrict__ pgk, const float* __restrict__ pgb) {
    int l = blockIdx.x * 256 + threadIdx.x;
    if (l >= NL) return;
    float f0 = (cap[l] - 5.0f) * 0.25f;
    float f1 = load[l];
    float f2 = f1 / mll[0];
    float f3 = 8.0f / 32768.0f;
    float t1[16];
#pragma unroll
    for (int u = 0; u < 16; ++u) {
        float a = b1[u] + f0 * w1[u] + f1 * w1[16 + u] + f2 * w1[32 + u] + f3 * w1[48 + u];
        t1[u] = seluf(a);
    }
    float out[16];
#pragma unroll
    for (int u = 0; u < 16; ++u) {
        float a = b2[u];
#pragma unroll
        for (int i = 0; i < 16; ++i) a += t1[i] * w2[i * 16 + u];
        out[u] = seluf(a);
    }
    float4* o4 = (float4*)(ls + (size_t)l * 16);
    const float4* s4 = (const float4*)out;
#pragma unroll
    for (int q = 0; q < 4; ++q) o4[q] = s4[q];
    for (int u = 0; u < 48; ++u) {
        float a = pgb[u];
#pragma unroll
        for (int i = 0; i < 16; ++i) a += out[i] * pgk[i * 48 + u];
        xk[(size_t)l * XKS + u] = a;
    }
}

// ---------------- K1: path GRU via MFMA, 4 threads/flow, zero shuffles ----------------
// Wave = 16 flows. lane: fcol = lane&15 (flow), q = lane>>4 (dim quad).
// D[gate_dim][flow] = W^T · h : D-layout == B-layout => h feeds back with no x-lane ops.
// MODE 0: f32 seq [f][9][16]; MODE 1: bf16 seq [t][NF][16] rows 0..7;
// MODE 2: f32 seqF [f][8][16] rows 1..8 (KAN input)
template <int MODE>
__global__ __launch_bounds__(256) void k_path_mfma(
    const float* __restrict__ xk, const int* __restrict__ ltp,
    float* __restrict__ ps, unsigned short* __restrict__ seqb,
    float* __restrict__ seqf,
    const float* __restrict__ grk, const float* __restrict__ gb) {
    int tid = threadIdx.x;
    int lane = tid & 63;
    int fcol = lane & 15, q = lane >> 4;
    int f = blockIdx.x * 64 + (tid >> 6) * 16 + fcol;
    // A fragments: lane holds W[k = q*4+j][gate*16 + fcol]  (A row = fcol, A k = q*4+j)
    f16x4 Az, Ar, Ac;
#pragma unroll
    for (int j = 0; j < 4; ++j) {
        Az[j] = (_Float16)grk[(q * 4 + j) * 48 + fcol];
        Ar[j] = (_Float16)grk[(q * 4 + j) * 48 + 16 + fcol];
        Ac[j] = (_Float16)grk[(q * 4 + j) * 48 + 32 + fcol];
    }
    // h-side biases for dims d = q*4 + r
    float4 bgz = *(const float4*)(gb + 48 + q * 4);
    float4 bgr = *(const float4*)(gb + 64 + q * 4);
    float4 bgc = *(const float4*)(gb + 80 + q * 4);
    float4 h0 = *(const float4*)(ps + (size_t)f * 16 + q * 4);
    f32x4 h = {h0.x, h0.y, h0.z, h0.w};
    int4 lt0 = *(const int4*)(ltp + (size_t)f * 8);
    int4 lt1 = *(const int4*)(ltp + (size_t)f * 8 + 4);
    if (MODE == 0) {
        *(float4*)(seqf + (size_t)f * 9 * 16 + q * 4) = h0;
    } else if (MODE == 1) {
        ushort4 u4;
        u4.x = f2bf(h[0]); u4.y = f2bf(h[1]); u4.z = f2bf(h[2]); u4.w = f2bf(h[3]);
        *(ushort4*)(seqb + (size_t)f * 16 + q * 4) = u4;  // row 0
    }
#pragma unroll
    for (int t = 0; t < 8; ++t) {
        int lk = (t == 0) ? lt0.x : (t == 1) ? lt0.y : (t == 2) ? lt0.z : (t == 3) ? lt0.w
               : (t == 4) ? lt1.x : (t == 5) ? lt1.y : (t == 6) ? lt1.z : lt1.w;
        const float* xb = xk + (size_t)lk * XKS;
        float4 xz = *(const float4*)(xb + q * 4);
        float4 xr = *(const float4*)(xb + 16 + q * 4);
        float4 xc = *(const float4*)(xb + 32 + q * 4);
        f16x4 hb;
#pragma unroll
        for (int r = 0; r < 4; ++r) hb[r] = (_Float16)h[r];
        f32x4 accZ = {xz.x + bgz.x, xz.y + bgz.y, xz.z + bgz.z, xz.w + bgz.w};
        f32x4 accR = {xr.x + bgr.x, xr.y + bgr.y, xr.z + bgr.z, xr.w + bgr.w};
        f32x4 accC = {bgc.x, bgc.y, bgc.z, bgc.w};
        accZ = __builtin_amdgcn_mfma_f32_16x16x16f16(Az, hb, accZ, 0, 0, 0);
        accR = __builtin_amdgcn_mfma_f32_16x16x16f16(Ar, hb, accR, 0, 0, 0);
        accC = __builtin_amdgcn_mfma_f32_16x16x16f16(Ac, hb, accC, 0, 0, 0);
        float xc0 = xc.x, xc1 = xc.y, xc2 = xc.z, xc3 = xc.w;
        {
            float z = sigm(accZ[0]), rr = sigm(accR[0]);
            float c = tanhfast(xc0 + rr * accC[0]);
            h[0] = z * h[0] + (1.0f - z) * c;
            z = sigm(accZ[1]); rr = sigm(accR[1]);
            c = tanhfast(xc1 + rr * accC[1]);
            h[1] = z * h[1] + (1.0f - z) * c;
            z = sigm(accZ[2]); rr = sigm(accR[2]);
            c = tanhfast(xc2 + rr * accC[2]);
            h[2] = z * h[2] + (1.0f - z) * c;
            z = sigm(accZ[3]); rr = sigm(accR[3]);
            c = tanhfast(xc3 + rr * accC[3]);
            h[3] = z * h[3] + (1.0f - z) * c;
        }
        if (MODE == 0) {
            float4 st = {h[0], h[1], h[2], h[3]};
            *(float4*)(seqf + ((size_t)f * 9 + t + 1) * 16 + q * 4) = st;
        } else if (MODE == 1) {
            if (t < 7) {  // row 8 never gathered (p_pos < 8)
                ushort4 u4;
                u4.x = f2bf(h[0]); u4.y = f2bf(h[1]); u4.z = f2bf(h[2]); u4.w = f2bf(h[3]);
                *(ushort4*)(seqb + ((size_t)(t + 1) * NF + f) * 16 + q * 4) = u4;
            }
        } else {
            float4 st = {h[0], h[1], h[2], h[3]};
            *(float4*)(seqf + ((size_t)f * 8 + t) * 16 + q * 4) = st;
        }
    }
    if (MODE != 2) {
        float4 st = {h[0], h[1], h[2], h[3]};
        *(float4*)(ps + (size_t)f * 16 + q * 4) = st;
    }
}

// ---------------- K2: attention message + link GRU (+ xk fold) ----------------
// Round-3 proven structure: LDS-tree reduction, serial-16 GRU tail.
template <bool BF16>
__global__ __launch_bounds__(128) void k_link_upd(
    const void* __restrict__ seqv, const int* __restrict__ p2l,
    float* __restrict__ ls,
    const float* __restrict__ aw, const float* __restrict__ ab,
    const float* __restrict__ gk, const float* __restrict__ grk,
    const float* __restrict__ gb,
    float* __restrict__ xk, const float* __restrict__ pgk,
    const float* __restrict__ pgb) {
    __shared__ float sW[256], sB[16], red[128][17], sh[16], sh2[16];
    int tid = threadIdx.x;
    int link = blockIdx.x;
    sW[tid] = aw[tid];
    sW[tid + 128] = aw[tid + 128];
    if (tid < 16) sB[tid] = ab[tid];
    __syncthreads();
    int2 pp = ((const int2*)p2l)[(size_t)link * PPL + tid];
    float pg[16];
    if (BF16) {
        const unsigned short* sp =
            (const unsigned short*)seqv + ((size_t)pp.y * NF + pp.x) * 16;
        uint4 q0 = *(const uint4*)sp;
        uint4 q1 = *(const uint4*)(sp + 8);
        pg[0] = bflo(q0.x); pg[1] = bfhi(q0.x); pg[2] = bflo(q0.y); pg[3] = bfhi(q0.y);
        pg[4] = bflo(q0.z); pg[5] = bfhi(q0.z); pg[6] = bflo(q0.w); pg[7] = bfhi(q0.w);
        pg[8] = bflo(q1.x); pg[9] = bfhi(q1.x); pg[10] = bflo(q1.y); pg[11] = bfhi(q1.y);
        pg[12] = bflo(q1.z); pg[13] = bfhi(q1.z); pg[14] = bflo(q1.w); pg[15] = bfhi(q1.w);
    } else {
        const float4* pv =
            (const float4*)((const float*)seqv + ((size_t)pp.x * 9 + pp.y) * 16);
        float4* pr = (float4*)pg;
        pr[0] = pv[0]; pr[1] = pv[1]; pr[2] = pv[2]; pr[3] = pv[3];
    }
    float at[16];
#pragma unroll
    for (int u = 0; u < 16; ++u) {
        float a = sB[u];
#pragma unroll
        for (int i = 0; i < 16; ++i) a += pg[i] * sW[i * 16 + u];
        at[u] = a > 0.0f ? a : 0.01f * a;
    }
    float mx = at[0];
#pragma unroll
    for (int u = 1; u < 16; ++u) mx = fmaxf(mx, at[u]);
    float e[16];
    float ssum = 0.0f;
#pragma unroll
    for (int u = 0; u < 16; ++u) { e[u] = __expf(at[u] - mx); ssum += e[u]; }
    float inv = 1.0f / ssum;
#pragma unroll
    for (int u = 0; u < 16; ++u) red[tid][u] = e[u] * inv * pg[u];
    __syncthreads();
    for (int s = 64; s > 0; s >>= 1) {
        if (tid < s) {
#pragma unroll
            for (int u = 0; u < 16; ++u) red[tid][u] += red[tid + s][u];
        }
        __syncthreads();
    }
    if (tid < 16) sh[tid] = ls[(size_t)link * 16 + tid];
    __syncthreads();
    if (tid < 16) {
        int d = tid;
        float az = gb[d], ar = gb[16 + d], ac = gb[32 + d];
        float gz = gb[48 + d], gr = gb[64 + d], gc = gb[80 + d];
#pragma unroll
        for (int i = 0; i < 16; ++i) {
            float mi = red[0][i];
            float hi = sh[i];
            az += mi * gk[i * 48 + d];
            ar += mi * gk[i * 48 + 16 + d];
            ac += mi * gk[i * 48 + 32 + d];
            gz += hi * grk[i * 48 + d];
            gr += hi * grk[i * 48 + 16 + d];
            gc += hi * grk[i * 48 + 32 + d];
        }
        float z = sigm(az + gz);
        float r = sigm(ar + gr);
        float c = tanhfast(ac + r * gc);
        float hn = z * sh[d] + (1.0f - z) * c;
        ls[(size_t)link * 16 + d] = hn;
        sh2[d] = hn;
    }
    __syncthreads();
    if (tid < 48) {
        float a = pgb[tid];
#pragma unroll
        for (int i = 0; i < 16; ++i) a += sh2[i] * pgk[i * 48 + tid];
        xk[(size_t)link * XKS + tid] = a;
    }
}

// ---------------- K4: KAN readout (sparse 4-basis spline) ----------------
template <int M>
__global__ __launch_bounds__(256) void k_kan(
    const float* __restrict__ seqf, const int* __restrict__ ltp,
    const float* __restrict__ cap,
    const float* __restrict__ sp1, const float* __restrict__ ba1,
    const float* __restrict__ bi1,
    const float* __restrict__ sp2, const float* __restrict__ ba2,
    const float* __restrict__ bi2,
    float* __restrict__ out) {
    // padded spline tables: rows r = jj+3, jj in [0,8) real, else 0
    __shared__ float s1p[16 * 14 * 16];  // [i][r][u]
    __shared__ float s2p[16 * 14];       // [i][r]
    __shared__ float sba1[256], sbi1[16], sba2[16];
    int tid = threadIdx.x;
    for (int k = tid; k < 16 * 14 * 16; k += 256) {
        int u = k & 15;
        int r = (k >> 4) % 14;
        int i = k / (14 * 16);
        int jj = r - 3;
        s1p[k] = (jj >= 0 && jj < 8) ? sp1[(i * 8 + jj) * 16 + u] : 0.0f;
    }
    for (int k = tid; k < 16 * 14; k += 256) {
        int r = k % 14;
        int i = k / 14;
        int jj = r - 3;
        s2p[k] = (jj >= 0 && jj < 8) ? sp2[i * 8 + jj] : 0.0f;
    }
    sba1[tid] = ba1[tid];
    if (tid < 16) { sbi1[tid] = bi1[tid]; sba2[tid] = ba2[tid]; }
    __syncthreads();
    int gt = blockIdx.x * 256 + tid;
    int f = gt >> 3, t = gt & 7;
    float x[16];
    {
        const float4* xv = (M == 0)
            ? (const float4*)(seqf + ((size_t)f * 9 + 1 + t) * 16)
            : (const float4*)(seqf + ((size_t)f * 8 + t) * 16);
        float4* xr = (float4*)x;
        xr[0] = xv[0]; xr[1] = xv[1]; xr[2] = xv[2]; xr[3] = xv[3];
    }
    float hh[16];
#pragma unroll
    for (int u = 0; u < 16; ++u) hh[u] = sbi1[u];
#pragma unroll
    for (int i = 0; i < 16; ++i) {
        float B0, B1, B2, B3;
        int idx = bspline4(x[i], B0, B1, B2, B3);
        const float* row = s1p + (i * 14 + idx) * 16;
#pragma unroll
        for (int u = 0; u < 16; ++u)
            hh[u] += B0 * row[u] + B1 * row[16 + u] + B2 * row[32 + u] + B3 * row[48 + u];
        float sil = x[i] * sigm(x[i]);
#pragma unroll
        for (int u = 0; u < 16; ++u) hh[u] += sil * sba1[i * 16 + u];
    }
    float occ = bi2[0];
#pragma unroll
    for (int i = 0; i < 16; ++i) {
        float B0, B1, B2, B3;
        int idx = bspline4(hh[i], B0, B1, B2, B3);
        const float* rw = s2p + i * 14 + idx;
        occ += B0 * rw[0] + B1 * rw[1] + B2 * rw[2] + B3 * rw[3];
        occ += hh[i] * sigm(hh[i]) * sba2[i];
    }
    int lk = ltp[(size_t)f * 8 + t];
    float val = occ / cap[lk];
#pragma unroll
    for (int off = 4; off; off >>= 1) val += __shfl_xor(val, off, 8);
    if (t == 0) out[f] = val;
}

extern "C" void kernel_launch(void* const* d_in, const int* in_sizes, int n_in,
                              void* d_out, int out_size, void* d_ws, size_t ws_size,
                              hipStream_t stream) {
    const float* f_tr   = (const float*)d_in[0];
    const float* f_pk   = (const float*)d_in[1];
    const float* f_ppb  = (const float*)d_in[2];
    const float* f_bpb  = (const float*)d_in[3];
    const float* f_psz  = (const float*)d_in[4];
    const float* f_p90  = (const float*)d_in[5];
    const float* f_rate = (const float*)d_in[6];
    const float* f_ipgm = (const float*)d_in[7];
    const float* f_ibg  = (const float*)d_in[8];
    const float* f_ipgv = (const float*)d_in[9];
    const float* f_type = (const float*)d_in[10];
    const float* f_cap  = (const float*)d_in[11];
    const float* f_mll  = (const float*)d_in[12];
    const int*   i_flen = (const int*)d_in[13];
    const int*   i_ltp  = (const int*)d_in[15];
    const int*   i_p2l  = (const int*)d_in[16];
    const float* fe_w1 = (const float*)d_in[17];
    const float* fe_b1 = (const float*)d_in[18];
    const float* fe_w2 = (const float*)d_in[19];
    const float* fe_b2 = (const float*)d_in[20];
    const float* le_w1 = (const float*)d_in[21];
    const float* le_b1 = (const float*)d_in[22];
    const float* le_w2 = (const float*)d_in[23];
    const float* le_b2 = (const float*)d_in[24];
    const float* at_w  = (const float*)d_in[25];
    const float* at_b  = (const float*)d_in[26];
    const float* pg_k  = (const float*)d_in[27];
    const float* pg_rk = (const float*)d_in[28];
    const float* pg_b  = (const float*)d_in[29];
    const float* lg_k  = (const float*)d_in[30];
    const float* lg_rk = (const float*)d_in[31];
    const float* lg_b  = (const float*)d_in[32];
    const float* k1_sp = (const float*)d_in[33];
    const float* k1_ba = (const float*)d_in[34];
    const float* k1_bi = (const float*)d_in[35];
    const float* k2_sp = (const float*)d_in[36];
    const float* k2_ba = (const float*)d_in[37];
    const float* k2_bi = (const float*)d_in[38];

    float* ws = (float*)d_ws;
    float* ps   = ws;
    float* ls   = ps + (size_t)NF * 16;
    float* xk   = ls + (size_t)NL * 16;
    float* load = xk + (size_t)NL * XKS;
    float* tail = load + NL;
    size_t head_bytes = (size_t)(tail - ws) * 4;
    unsigned short* seqb = (unsigned short*)tail;          // bf16 [8][NF][16]
    size_t seqb_elems = (size_t)NF * 8 * 16;
    float* seqfL = (float*)(seqb + seqb_elems);            // f32 [NF][8][16]
    size_t need_bf = head_bytes + seqb_elems * 2 + (size_t)NF * 8 * 16 * 4;
    float* seq32 = tail;                                   // fallback f32 [NF][9][16]
    bool bfp = ws_size >= need_bf;
    float* out = (float*)d_out;

    k_load<<<NL * 64 / 256, 256, 0, stream>>>(i_p2l, f_tr, f_cap, load);
    k_flow_enc<<<NF / 256, 256, 0, stream>>>(f_tr, f_pk, f_ppb, f_bpb, f_psz, f_p90,
                                             f_rate, f_ipgm, f_ibg, f_ipgv, f_type,
                                             i_flen, fe_w1, fe_b1, fe_w2, fe_b2, ps);
    k_link_enc<<<NL / 256, 256, 0, stream>>>(f_cap, load, f_mll, le_w1, le_b1, le_w2,
                                             le_b2, ls, xk, pg_k, pg_b);
    if (bfp) {
        for (int it = 0; it < 12; ++it) {
            if (it < 11) {
                k_path_mfma<1><<<NF / 64, 256, 0, stream>>>(xk, i_ltp, ps, seqb,
                                                            nullptr, pg_rk, pg_b);
                k_link_upd<true><<<NL, 128, 0, stream>>>(seqb, i_p2l, ls, at_w, at_b,
                                                         lg_k, lg_rk, lg_b, xk, pg_k, pg_b);
            } else {
                k_path_mfma<2><<<NF / 64, 256, 0, stream>>>(xk, i_ltp, ps, nullptr,
                                                            seqfL, pg_rk, pg_b);
            }
        }
        k_kan<1><<<NF * 8 / 256, 256, 0, stream>>>(seqfL, i_ltp, f_cap, k1_sp, k1_ba,
                                                   k1_bi, k2_sp, k2_ba, k2_bi, out);
    } else {
        for (int it = 0; it < 12; ++it) {
            k_path_mfma<0><<<NF / 64, 256, 0, stream>>>(xk, i_ltp, ps, nullptr,
                                                        seq32, pg_rk, pg_b);
            if (it < 11)
                k_link_upd<false><<<NL, 128, 0, stream>>>(seq32, i_p2l, ls, at_w, at_b,
                                                          lg_k, lg_rk, lg_b, xk, pg_k, pg_b);
        }
        k_kan<0><<<NF * 8 / 256, 256, 0, stream>>>(seq32, i_ltp, f_cap, k1_sp, k1_ba,
                                                   k1_bi, k2_sp, k2_ba, k2_bi, out);
    }
}

// Round 8
// 498.527 us; speedup vs baseline: 1.9298x; 1.3898x over previous
//
#include <hip/hip_runtime.h>
#include <cstdint>

#define NF 65536
#define PL 8
#define NL 4096
#define PPL 128
#define XKS 64  // padded xk record stride (floats): 256 B, cacheline-aligned

typedef _Float16 f16x4 __attribute__((ext_vector_type(4)));
typedef float f32x4 __attribute__((ext_vector_type(4)));

__device__ __forceinline__ float sigm(float v) { return 1.0f / (1.0f + __expf(-v)); }
__device__ __forceinline__ float tanhfast(float v) {
    float e = __expf(2.0f * v);
    return 1.0f - 2.0f / (e + 1.0f);
}
__device__ __forceinline__ float seluf(float x) {
    return x > 0.0f ? 1.0507009873554805f * x : 1.7580993408473766f * (__expf(x) - 1.0f);
}
__device__ __forceinline__ unsigned short f2bf(float x) {
    unsigned u = __float_as_uint(x);
    u += 0x7fffu + ((u >> 16) & 1u);
    return (unsigned short)(u >> 16);
}
__device__ __forceinline__ float bfu(unsigned short us) {
    return __uint_as_float((unsigned)us << 16);
}
// hi/lo split: x ~= hi + lo with ~22 combined mantissa bits
__device__ __forceinline__ void splitf(float x, _Float16& hi, _Float16& lo) {
    _Float16 h = (_Float16)x;
    hi = h;
    lo = (_Float16)(x - (float)h);
}
// compensated matvec: A*B with A=Ah+Al, B=Bh+Bl (drop Al*Bl ~ 2^-22)
__device__ __forceinline__ f32x4 mfma3(f16x4 Ah, f16x4 Al, f16x4 Bh, f16x4 Bl,
                                       f32x4 acc) {
    acc = __builtin_amdgcn_mfma_f32_16x16x16f16(Ah, Bh, acc, 0, 0, 0);
    acc = __builtin_amdgcn_mfma_f32_16x16x16f16(Al, Bh, acc, 0, 0, 0);
    acc = __builtin_amdgcn_mfma_f32_16x16x16f16(Ah, Bl, acc, 0, 0, 0);
    return acc;
}

// Sparse cubic B-spline: 4 active bases at local u, interval idx. Uniform knots
// t_j = (j-3)*0.4 - 1 (identical to jnp _knots pyramid; closed-form is exact).
__device__ __forceinline__ int bspline4(float xx, float& B0, float& B1, float& B2,
                                        float& B3) {
    const float KN0 = (0 - 3) * 0.4f - 1.0f;    // t_0  = -2.2
    float s = (xx - KN0) * 2.5f;
    int idx = (int)floorf(s);
    bool valid = (idx >= 0) && (idx <= 10);     // outside [t_0, t_11): all bases 0
    idx = min(max(idx, 0), 10);
    float tI = (float)(idx - 3) * 0.4f - 1.0f;
    float u = (xx - tI) * 2.5f;
    float um = 1.0f - u;
    float u2 = u * u, u3 = u2 * u;
    B0 = um * um * um * (1.0f / 6.0f);
    B1 = 0.5f * u3 - u2 + (2.0f / 3.0f);
    B2 = -0.5f * u3 + 0.5f * u2 + 0.5f * u + (1.0f / 6.0f);
    B3 = u3 * (1.0f / 6.0f);
    if (!valid) { B0 = 0.f; B1 = 0.f; B2 = 0.f; B3 = 0.f; }
    return idx;
}

// ---------------- S1: per-link load ----------------
__global__ __launch_bounds__(256) void k_load(const int* __restrict__ p2l,
                                              const float* __restrict__ ft,
                                              const float* __restrict__ cap,
                                              float* __restrict__ load) {
    int gid = blockIdx.x * 256 + threadIdx.x;
    int link = gid >> 6;
    int lane = threadIdx.x & 63;
    const int2* b2 = (const int2*)(p2l + (size_t)link * PPL * 2);
    int2 v0 = b2[lane];
    int2 v1 = b2[lane + 64];
    float s = ft[v0.x] + ft[v1.x];
#pragma unroll
    for (int off = 32; off; off >>= 1) s += __shfl_xor(s, off);
    if (lane == 0) load[link] = s / (cap[link] * 1e9f);
}

// ---------------- S2: flow encoder -> path_state ----------------
__global__ __launch_bounds__(256) void k_flow_enc(
    const float* __restrict__ tr, const float* __restrict__ pk,
    const float* __restrict__ ppb, const float* __restrict__ bpb,
    const float* __restrict__ psz, const float* __restrict__ p90,
    const float* __restrict__ rate, const float* __restrict__ ipgm,
    const float* __restrict__ ibg, const float* __restrict__ ipgv,
    const float* __restrict__ ftype, const int* __restrict__ flen,
    const float* __restrict__ w1, const float* __restrict__ b1,
    const float* __restrict__ w2, const float* __restrict__ b2,
    float* __restrict__ ps) {
    __shared__ float sw1[13 * 16], sb1[16], sw2[256], sb2[16];
    int tid = threadIdx.x;
    if (tid < 208) sw1[tid] = w1[tid];
    sw2[tid] = w2[tid];
    if (tid < 16) { sb1[tid] = b1[tid]; sb2[tid] = b2[tid]; }
    __syncthreads();
    int f = blockIdx.x * 256 + tid;
    float feat[13];
    feat[0] = (tr[f] - 0.5f) * 2.0f;
    feat[1] = (pk[f] - 0.5f) * 2.0f;
    feat[2] = (ibg[f] - 0.5f) * 2.0f;
    feat[3] = (rate[f] - 0.5f) * 2.0f;
    feat[4] = (p90[f] - 0.5f) * 2.0f;
    feat[5] = (psz[f] - 0.5f) * 2.0f;
    feat[6] = (bpb[f] - 0.5f) * 2.0f;
    feat[7] = (ipgm[f] - 0.5f) * 2.0f;
    feat[8] = (ipgv[f] - 0.5f) * 2.0f;
    feat[9] = (ppb[f] - 0.5f) * 2.0f;
    feat[10] = (float)flen[f];
    float2 ft2 = ((const float2*)ftype)[f];
    feat[11] = ft2.x;
    feat[12] = ft2.y;
    float t1[16];
#pragma unroll
    for (int u = 0; u < 16; ++u) {
        float a = sb1[u];
#pragma unroll
        for (int i = 0; i < 13; ++i) a += feat[i] * sw1[i * 16 + u];
        t1[u] = seluf(a);
    }
    float out[16];
#pragma unroll
    for (int u = 0; u < 16; ++u) {
        float a = sb2[u];
#pragma unroll
        for (int i = 0; i < 16; ++i) a += t1[i] * sw2[i * 16 + u];
        out[u] = seluf(a);
    }
    float4* o4 = (float4*)(ps + (size_t)f * 16);
    const float4* s4 = (const float4*)out;
#pragma unroll
    for (int q = 0; q < 4; ++q) o4[q] = s4[q];
}

// ---------------- S3: link encoder -> link_state (+ xk fold) ----------------
__global__ __launch_bounds__(256) void k_link_enc(
    const float* __restrict__ cap, const float* __restrict__ load,
    const float* __restrict__ mll,
    const float* __restrict__ w1, const float* __restrict__ b1,
    const float* __restrict__ w2, const float* __restrict__ b2,
    float* __restrict__ ls, float* __restrict__ xk,
    const float* __restrict__ pgk, const float* __restrict__ pgb) {
    int l = blockIdx.x * 256 + threadIdx.x;
    if (l >= NL) return;
    float f0 = (cap[l] - 5.0f) * 0.25f;
    float f1 = load[l];
    float f2 = f1 / mll[0];
    float f3 = 8.0f / 32768.0f;
    float t1[16];
#pragma unroll
    for (int u = 0; u < 16; ++u) {
        float a = b1[u] + f0 * w1[u] + f1 * w1[16 + u] + f2 * w1[32 + u] + f3 * w1[48 + u];
        t1[u] = seluf(a);
    }
    float out[16];
#pragma unroll
    for (int u = 0; u < 16; ++u) {
        float a = b2[u];
#pragma unroll
        for (int i = 0; i < 16; ++i) a += t1[i] * w2[i * 16 + u];
        out[u] = seluf(a);
    }
    float4* o4 = (float4*)(ls + (size_t)l * 16);
    const float4* s4 = (const float4*)out;
#pragma unroll
    for (int q = 0; q < 4; ++q) o4[q] = s4[q];
    for (int u = 0; u < 48; ++u) {
        float a = pgb[u];
#pragma unroll
        for (int i = 0; i < 16; ++i) a += out[i] * pgk[i * 48 + u];
        xk[(size_t)l * XKS + u] = a;
    }
}

// ---------------- K1: path GRU via MFMA (round-6 proven) ----------------
template <int MODE>
__global__ __launch_bounds__(256) void k_path_mfma(
    const float* __restrict__ xk, const int* __restrict__ ltp,
    float* __restrict__ ps, unsigned short* __restrict__ seqb,
    float* __restrict__ seqf,
    const float* __restrict__ grk, const float* __restrict__ gb) {
    int tid = threadIdx.x;
    int lane = tid & 63;
    int fcol = lane & 15, q = lane >> 4;
    int f = blockIdx.x * 64 + (tid >> 6) * 16 + fcol;
    f16x4 Az, Ar, Ac;
#pragma unroll
    for (int j = 0; j < 4; ++j) {
        Az[j] = (_Float16)grk[(q * 4 + j) * 48 + fcol];
        Ar[j] = (_Float16)grk[(q * 4 + j) * 48 + 16 + fcol];
        Ac[j] = (_Float16)grk[(q * 4 + j) * 48 + 32 + fcol];
    }
    float4 bgz = *(const float4*)(gb + 48 + q * 4);
    float4 bgr = *(const float4*)(gb + 64 + q * 4);
    float4 bgc = *(const float4*)(gb + 80 + q * 4);
    float4 h0 = *(const float4*)(ps + (size_t)f * 16 + q * 4);
    f32x4 h = {h0.x, h0.y, h0.z, h0.w};
    int4 lt0 = *(const int4*)(ltp + (size_t)f * 8);
    int4 lt1 = *(const int4*)(ltp + (size_t)f * 8 + 4);
    if (MODE == 0) {
        *(float4*)(seqf + (size_t)f * 9 * 16 + q * 4) = h0;
    } else if (MODE == 1) {
        ushort4 u4;
        u4.x = f2bf(h[0]); u4.y = f2bf(h[1]); u4.z = f2bf(h[2]); u4.w = f2bf(h[3]);
        *(ushort4*)(seqb + (size_t)f * 16 + q * 4) = u4;  // row 0
    }
#pragma unroll
    for (int t = 0; t < 8; ++t) {
        int lk = (t == 0) ? lt0.x : (t == 1) ? lt0.y : (t == 2) ? lt0.z : (t == 3) ? lt0.w
               : (t == 4) ? lt1.x : (t == 5) ? lt1.y : (t == 6) ? lt1.z : lt1.w;
        const float* xb = xk + (size_t)lk * XKS;
        float4 xz = *(const float4*)(xb + q * 4);
        float4 xr = *(const float4*)(xb + 16 + q * 4);
        float4 xc = *(const float4*)(xb + 32 + q * 4);
        f16x4 hb;
#pragma unroll
        for (int r = 0; r < 4; ++r) hb[r] = (_Float16)h[r];
        f32x4 accZ = {xz.x + bgz.x, xz.y + bgz.y, xz.z + bgz.z, xz.w + bgz.w};
        f32x4 accR = {xr.x + bgr.x, xr.y + bgr.y, xr.z + bgr.z, xr.w + bgr.w};
        f32x4 accC = {bgc.x, bgc.y, bgc.z, bgc.w};
        accZ = __builtin_amdgcn_mfma_f32_16x16x16f16(Az, hb, accZ, 0, 0, 0);
        accR = __builtin_amdgcn_mfma_f32_16x16x16f16(Ar, hb, accR, 0, 0, 0);
        accC = __builtin_amdgcn_mfma_f32_16x16x16f16(Ac, hb, accC, 0, 0, 0);
        float xc0 = xc.x, xc1 = xc.y, xc2 = xc.z, xc3 = xc.w;
        {
            float z = sigm(accZ[0]), rr = sigm(accR[0]);
            float c = tanhfast(xc0 + rr * accC[0]);
            h[0] = z * h[0] + (1.0f - z) * c;
            z = sigm(accZ[1]); rr = sigm(accR[1]);
            c = tanhfast(xc1 + rr * accC[1]);
            h[1] = z * h[1] + (1.0f - z) * c;
            z = sigm(accZ[2]); rr = sigm(accR[2]);
            c = tanhfast(xc2 + rr * accC[2]);
            h[2] = z * h[2] + (1.0f - z) * c;
            z = sigm(accZ[3]); rr = sigm(accR[3]);
            c = tanhfast(xc3 + rr * accC[3]);
            h[3] = z * h[3] + (1.0f - z) * c;
        }
        if (MODE == 0) {
            float4 st = {h[0], h[1], h[2], h[3]};
            *(float4*)(seqf + ((size_t)f * 9 + t + 1) * 16 + q * 4) = st;
        } else if (MODE == 1) {
            if (t < 7) {
                ushort4 u4;
                u4.x = f2bf(h[0]); u4.y = f2bf(h[1]); u4.z = f2bf(h[2]); u4.w = f2bf(h[3]);
                *(ushort4*)(seqb + ((size_t)(t + 1) * NF + f) * 16 + q * 4) = u4;
            }
        } else {
            float4 st = {h[0], h[1], h[2], h[3]};
            *(float4*)(seqf + ((size_t)f * 8 + t) * 16 + q * 4) = st;
        }
    }
    if (MODE != 2) {
        float4 st = {h[0], h[1], h[2], h[3]};
        *(float4*)(ps + (size_t)f * 16 + q * 4) = st;
    }
}

// ---------------- K2: link update via MFMA with hi/lo compensation ----------------
// Structure validated in round 7 (error was precision-only); all matvecs now use
// split-f16 products => ~f32 accuracy, zero LDS, zero barriers.
template <bool BF16>
__global__ __launch_bounds__(256) void k_link_mfma(
    const void* __restrict__ seqv, const int* __restrict__ p2l,
    float* __restrict__ ls,
    const float* __restrict__ aw, const float* __restrict__ ab,
    const float* __restrict__ gk, const float* __restrict__ grk,
    const float* __restrict__ gb,
    float* __restrict__ xk, const float* __restrict__ pgk,
    const float* __restrict__ pgb) {
    int tid = threadIdx.x;
    int lane = tid & 63;
    int m = lane & 15, q = lane >> 4;
    int link = blockIdx.x * 4 + (tid >> 6);
    // A fragments (wave-uniform weights) split hi/lo: frag[j] = A[m][k=q*4+j]
    f16x4 AatH, AatL, Agk0H, Agk0L, Agk1H, Agk1L, Agk2H, Agk2L;
    f16x4 Agr0H, Agr0L, Agr1H, Agr1L, Agr2H, Agr2L;
    f16x4 Apg0H, Apg0L, Apg1H, Apg1L, Apg2H, Apg2L;
#pragma unroll
    for (int j = 0; j < 4; ++j) {
        int k = q * 4 + j;
        _Float16 hh, ll;
        splitf(aw[k * 16 + m], hh, ll); AatH[j] = hh; AatL[j] = ll;
        splitf(gk[k * 48 + m], hh, ll); Agk0H[j] = hh; Agk0L[j] = ll;
        splitf(gk[k * 48 + 16 + m], hh, ll); Agk1H[j] = hh; Agk1L[j] = ll;
        splitf(gk[k * 48 + 32 + m], hh, ll); Agk2H[j] = hh; Agk2L[j] = ll;
        splitf(grk[k * 48 + m], hh, ll); Agr0H[j] = hh; Agr0L[j] = ll;
        splitf(grk[k * 48 + 16 + m], hh, ll); Agr1H[j] = hh; Agr1L[j] = ll;
        splitf(grk[k * 48 + 32 + m], hh, ll); Agr2H[j] = hh; Agr2L[j] = ll;
        splitf(pgk[k * 48 + m], hh, ll); Apg0H[j] = hh; Apg0L[j] = ll;
        splitf(pgk[k * 48 + 16 + m], hh, ll); Apg1H[j] = hh; Apg1L[j] = ll;
        splitf(pgk[k * 48 + 32 + m], hh, ll); Apg2H[j] = hh; Apg2L[j] = ll;
    }
    float4 abf = *(const float4*)(ab + q * 4);
    float4 hq = *(const float4*)(ls + (size_t)link * 16 + q * 4);
    const int2* ppb = (const int2*)p2l + (size_t)link * PPL;
    int2 pp[8];
#pragma unroll
    for (int ch = 0; ch < 8; ++ch) pp[ch] = ppb[ch * 16 + m];
    f32x4 macc = {0.f, 0.f, 0.f, 0.f};
#pragma unroll
    for (int ch = 0; ch < 8; ++ch) {
        float p0, p1, p2, p3;
        if (BF16) {
            const unsigned short* sp =
                (const unsigned short*)seqv + ((size_t)pp[ch].y * NF + pp[ch].x) * 16 + q * 4;
            ushort4 u4 = *(const ushort4*)sp;
            p0 = bfu(u4.x); p1 = bfu(u4.y); p2 = bfu(u4.z); p3 = bfu(u4.w);
        } else {
            float4 v = *(const float4*)((const float*)seqv +
                                        ((size_t)pp[ch].x * 9 + pp[ch].y) * 16 + q * 4);
            p0 = v.x; p1 = v.y; p2 = v.z; p3 = v.w;
        }
        f16x4 BpgH, BpgL;
        {
            _Float16 hh, ll;
            splitf(p0, hh, ll); BpgH[0] = hh; BpgL[0] = ll;
            splitf(p1, hh, ll); BpgH[1] = hh; BpgL[1] = ll;
            splitf(p2, hh, ll); BpgH[2] = hh; BpgL[2] = ll;
            splitf(p3, hh, ll); BpgH[3] = hh; BpgL[3] = ll;
        }
        f32x4 at = {abf.x, abf.y, abf.z, abf.w};
        at = mfma3(AatH, AatL, BpgH, BpgL, at);
        float a0 = at[0] > 0.f ? at[0] : 0.01f * at[0];
        float a1 = at[1] > 0.f ? at[1] : 0.01f * at[1];
        float a2 = at[2] > 0.f ? at[2] : 0.01f * at[2];
        float a3 = at[3] > 0.f ? at[3] : 0.01f * at[3];
        float mx = fmaxf(fmaxf(a0, a1), fmaxf(a2, a3));
        mx = fmaxf(mx, __shfl_xor(mx, 16));
        mx = fmaxf(mx, __shfl_xor(mx, 32));
        float e0 = __expf(a0 - mx), e1 = __expf(a1 - mx);
        float e2 = __expf(a2 - mx), e3 = __expf(a3 - mx);
        float s = e0 + e1 + e2 + e3;
        s += __shfl_xor(s, 16);
        s += __shfl_xor(s, 32);
        float inv = 1.0f / s;
        macc[0] += e0 * inv * p0;
        macc[1] += e1 * inv * p1;
        macc[2] += e2 * inv * p2;
        macc[3] += e3 * inv * p3;
    }
#pragma unroll
    for (int off = 1; off < 16; off <<= 1) {
        macc[0] += __shfl_xor(macc[0], off);
        macc[1] += __shfl_xor(macc[1], off);
        macc[2] += __shfl_xor(macc[2], off);
        macc[3] += __shfl_xor(macc[3], off);
    }
    // macc[r] = msg[q*4+r] (identical across m lanes) -> B fragment directly
    f16x4 BmsgH, BmsgL, BhH, BhL;
    {
        _Float16 hh, ll;
        splitf(macc[0], hh, ll); BmsgH[0] = hh; BmsgL[0] = ll;
        splitf(macc[1], hh, ll); BmsgH[1] = hh; BmsgL[1] = ll;
        splitf(macc[2], hh, ll); BmsgH[2] = hh; BmsgL[2] = ll;
        splitf(macc[3], hh, ll); BmsgH[3] = hh; BmsgL[3] = ll;
        splitf(hq.x, hh, ll); BhH[0] = hh; BhL[0] = ll;
        splitf(hq.y, hh, ll); BhH[1] = hh; BhL[1] = ll;
        splitf(hq.z, hh, ll); BhH[2] = hh; BhL[2] = ll;
        splitf(hq.w, hh, ll); BhH[3] = hh; BhL[3] = ll;
    }
    float4 bz = *(const float4*)(gb + q * 4);
    float4 br = *(const float4*)(gb + 16 + q * 4);
    float4 bc = *(const float4*)(gb + 32 + q * 4);
    float4 hz4 = *(const float4*)(gb + 48 + q * 4);
    float4 hr4 = *(const float4*)(gb + 64 + q * 4);
    float4 hc4 = *(const float4*)(gb + 80 + q * 4);
    f32x4 az = {bz.x, bz.y, bz.z, bz.w};
    f32x4 ar = {br.x, br.y, br.z, br.w};
    f32x4 ac = {bc.x, bc.y, bc.z, bc.w};
    f32x4 gz = {hz4.x, hz4.y, hz4.z, hz4.w};
    f32x4 gr = {hr4.x, hr4.y, hr4.z, hr4.w};
    f32x4 gc = {hc4.x, hc4.y, hc4.z, hc4.w};
    az = mfma3(Agk0H, Agk0L, BmsgH, BmsgL, az);
    ar = mfma3(Agk1H, Agk1L, BmsgH, BmsgL, ar);
    ac = mfma3(Agk2H, Agk2L, BmsgH, BmsgL, ac);
    gz = mfma3(Agr0H, Agr0L, BhH, BhL, gz);
    gr = mfma3(Agr1H, Agr1L, BhH, BhL, gr);
    gc = mfma3(Agr2H, Agr2L, BhH, BhL, gc);
    float hn0, hn1, hn2, hn3;
    {
        float z = sigm(az[0] + gz[0]), rr = sigm(ar[0] + gr[0]);
        float c = tanhfast(ac[0] + rr * gc[0]);
        hn0 = z * hq.x + (1.0f - z) * c;
        z = sigm(az[1] + gz[1]); rr = sigm(ar[1] + gr[1]);
        c = tanhfast(ac[1] + rr * gc[1]);
        hn1 = z * hq.y + (1.0f - z) * c;
        z = sigm(az[2] + gz[2]); rr = sigm(ar[2] + gr[2]);
        c = tanhfast(ac[2] + rr * gc[2]);
        hn2 = z * hq.z + (1.0f - z) * c;
        z = sigm(az[3] + gz[3]); rr = sigm(ar[3] + gr[3]);
        c = tanhfast(ac[3] + rr * gc[3]);
        hn3 = z * hq.w + (1.0f - z) * c;
    }
    if (m == 0) {
        float4 st = {hn0, hn1, hn2, hn3};
        *(float4*)(ls + (size_t)link * 16 + q * 4) = st;
    }
    f16x4 BhnH, BhnL;
    {
        _Float16 hh, ll;
        splitf(hn0, hh, ll); BhnH[0] = hh; BhnL[0] = ll;
        splitf(hn1, hh, ll); BhnH[1] = hh; BhnL[1] = ll;
        splitf(hn2, hh, ll); BhnH[2] = hh; BhnL[2] = ll;
        splitf(hn3, hh, ll); BhnH[3] = hh; BhnL[3] = ll;
    }
    float4 pb0 = *(const float4*)(pgb + q * 4);
    float4 pb1 = *(const float4*)(pgb + 16 + q * 4);
    float4 pb2 = *(const float4*)(pgb + 32 + q * 4);
    f32x4 x0 = {pb0.x, pb0.y, pb0.z, pb0.w};
    f32x4 x1 = {pb1.x, pb1.y, pb1.z, pb1.w};
    f32x4 x2 = {pb2.x, pb2.y, pb2.z, pb2.w};
    x0 = mfma3(Apg0H, Apg0L, BhnH, BhnL, x0);
    x1 = mfma3(Apg1H, Apg1L, BhnH, BhnL, x1);
    x2 = mfma3(Apg2H, Apg2L, BhnH, BhnL, x2);
    if (m == 0) {
        float4 s0 = {x0[0], x0[1], x0[2], x0[3]};
        float4 s1 = {x1[0], x1[1], x1[2], x1[3]};
        float4 s2 = {x2[0], x2[1], x2[2], x2[3]};
        float* xb = xk + (size_t)link * XKS;
        *(float4*)(xb + q * 4) = s0;
        *(float4*)(xb + 16 + q * 4) = s1;
        *(float4*)(xb + 32 + q * 4) = s2;
    }
}

// ---------------- K4: KAN readout (sparse spline, float4 LDS reads) ----------------
template <int M>
__global__ __launch_bounds__(256) void k_kan(
    const float* __restrict__ seqf, const int* __restrict__ ltp,
    const float* __restrict__ cap,
    const float* __restrict__ sp1, const float* __restrict__ ba1,
    const float* __restrict__ bi1,
    const float* __restrict__ sp2, const float* __restrict__ ba2,
    const float* __restrict__ bi2,
    float* __restrict__ out) {
    __shared__ float s1p[16 * 14 * 16];  // [i][idx pad14][u]
    __shared__ float s2q[16 * 11 * 4];   // [i][idx11][b] (zero-padded window)
    __shared__ float sba1[256], sbi1[16], sba2[16];
    int tid = threadIdx.x;
    for (int k = tid; k < 16 * 14 * 16; k += 256) {
        int u = k & 15;
        int r = (k >> 4) % 14;
        int i = k / (14 * 16);
        int jj = r - 3;
        s1p[k] = (jj >= 0 && jj < 8) ? sp1[(i * 8 + jj) * 16 + u] : 0.0f;
    }
    for (int k = tid; k < 16 * 11 * 4; k += 256) {
        int b = k & 3;
        int idx = (k >> 2) % 11;
        int i = k / 44;
        int jj = idx + b - 3;
        s2q[k] = (jj >= 0 && jj < 8) ? sp2[i * 8 + jj] : 0.0f;
    }
    sba1[tid] = ba1[tid];
    if (tid < 16) { sbi1[tid] = bi1[tid]; sba2[tid] = ba2[tid]; }
    __syncthreads();
    int gt = blockIdx.x * 256 + tid;
    int f = gt >> 3, t = gt & 7;
    float x[16];
    {
        const float4* xv = (M == 0)
            ? (const float4*)(seqf + ((size_t)f * 9 + 1 + t) * 16)
            : (const float4*)(seqf + ((size_t)f * 8 + t) * 16);
        float4* xr = (float4*)x;
        xr[0] = xv[0]; xr[1] = xv[1]; xr[2] = xv[2]; xr[3] = xv[3];
    }
    float hh[16];
#pragma unroll
    for (int u = 0; u < 16; ++u) hh[u] = sbi1[u];
#pragma unroll
    for (int i = 0; i < 16; ++i) {
        float B0, B1, B2, B3;
        int idx = bspline4(x[i], B0, B1, B2, B3);
        const float4* row4 = (const float4*)(s1p + (i * 14 + idx) * 16);
        const float4* sb4 = (const float4*)(sba1 + i * 16);
        float sil = x[i] * sigm(x[i]);
#pragma unroll
        for (int u4 = 0; u4 < 4; ++u4) {
            float4 r0 = row4[u4];
            float4 r1 = row4[4 + u4];
            float4 r2 = row4[8 + u4];
            float4 r3 = row4[12 + u4];
            float4 sb = sb4[u4];
            hh[4 * u4 + 0] += B0 * r0.x + B1 * r1.x + B2 * r2.x + B3 * r3.x + sil * sb.x;
            hh[4 * u4 + 1] += B0 * r0.y + B1 * r1.y + B2 * r2.y + B3 * r3.y + sil * sb.y;
            hh[4 * u4 + 2] += B0 * r0.z + B1 * r1.z + B2 * r2.z + B3 * r3.z + sil * sb.z;
            hh[4 * u4 + 3] += B0 * r0.w + B1 * r1.w + B2 * r2.w + B3 * r3.w + sil * sb.w;
        }
    }
    float occ = bi2[0];
#pragma unroll
    for (int i = 0; i < 16; ++i) {
        float B0, B1, B2, B3;
        int idx = bspline4(hh[i], B0, B1, B2, B3);
        float4 rw = *(const float4*)(s2q + (i * 11 + idx) * 4);
        occ += B0 * rw.x + B1 * rw.y + B2 * rw.z + B3 * rw.w;
        occ += hh[i] * sigm(hh[i]) * sba2[i];
    }
    int lk = ltp[(size_t)f * 8 + t];
    float val = occ / cap[lk];
#pragma unroll
    for (int off = 4; off; off >>= 1) val += __shfl_xor(val, off, 8);
    if (t == 0) out[f] = val;
}

extern "C" void kernel_launch(void* const* d_in, const int* in_sizes, int n_in,
                              void* d_out, int out_size, void* d_ws, size_t ws_size,
                              hipStream_t stream) {
    const float* f_tr   = (const float*)d_in[0];
    const float* f_pk   = (const float*)d_in[1];
    const float* f_ppb  = (const float*)d_in[2];
    const float* f_bpb  = (const float*)d_in[3];
    const float* f_psz  = (const float*)d_in[4];
    const float* f_p90  = (const float*)d_in[5];
    const float* f_rate = (const float*)d_in[6];
    const float* f_ipgm = (const float*)d_in[7];
    const float* f_ibg  = (const float*)d_in[8];
    const float* f_ipgv = (const float*)d_in[9];
    const float* f_type = (const float*)d_in[10];
    const float* f_cap  = (const float*)d_in[11];
    const float* f_mll  = (const float*)d_in[12];
    const int*   i_flen = (const int*)d_in[13];
    const int*   i_ltp  = (const int*)d_in[15];
    const int*   i_p2l  = (const int*)d_in[16];
    const float* fe_w1 = (const float*)d_in[17];
    const float* fe_b1 = (const float*)d_in[18];
    const float* fe_w2 = (const float*)d_in[19];
    const float* fe_b2 = (const float*)d_in[20];
    const float* le_w1 = (const float*)d_in[21];
    const float* le_b1 = (const float*)d_in[22];
    const float* le_w2 = (const float*)d_in[23];
    const float* le_b2 = (const float*)d_in[24];
    const float* at_w  = (const float*)d_in[25];
    const float* at_b  = (const float*)d_in[26];
    const float* pg_k  = (const float*)d_in[27];
    const float* pg_rk = (const float*)d_in[28];
    const float* pg_b  = (const float*)d_in[29];
    const float* lg_k  = (const float*)d_in[30];
    const float* lg_rk = (const float*)d_in[31];
    const float* lg_b  = (const float*)d_in[32];
    const float* k1_sp = (const float*)d_in[33];
    const float* k1_ba = (const float*)d_in[34];
    const float* k1_bi = (const float*)d_in[35];
    const float* k2_sp = (const float*)d_in[36];
    const float* k2_ba = (const float*)d_in[37];
    const float* k2_bi = (const float*)d_in[38];

    float* ws = (float*)d_ws;
    float* ps   = ws;
    float* ls   = ps + (size_t)NF * 16;
    float* xk   = ls + (size_t)NL * 16;
    float* load = xk + (size_t)NL * XKS;
    float* tail = load + NL;
    size_t head_bytes = (size_t)(tail - ws) * 4;
    unsigned short* seqb = (unsigned short*)tail;          // bf16 [8][NF][16]
    size_t seqb_elems = (size_t)NF * 8 * 16;
    float* seqfL = (float*)(seqb + seqb_elems);            // f32 [NF][8][16]
    size_t need_bf = head_bytes + seqb_elems * 2 + (size_t)NF * 8 * 16 * 4;
    float* seq32 = tail;                                   // fallback f32 [NF][9][16]
    bool bfp = ws_size >= need_bf;
    float* out = (float*)d_out;

    k_load<<<NL * 64 / 256, 256, 0, stream>>>(i_p2l, f_tr, f_cap, load);
    k_flow_enc<<<NF / 256, 256, 0, stream>>>(f_tr, f_pk, f_ppb, f_bpb, f_psz, f_p90,
                                             f_rate, f_ipgm, f_ibg, f_ipgv, f_type,
                                             i_flen, fe_w1, fe_b1, fe_w2, fe_b2, ps);
    k_link_enc<<<NL / 256, 256, 0, stream>>>(f_cap, load, f_mll, le_w1, le_b1, le_w2,
                                             le_b2, ls, xk, pg_k, pg_b);
    if (bfp) {
        for (int it = 0; it < 12; ++it) {
            if (it < 11) {
                k_path_mfma<1><<<NF / 64, 256, 0, stream>>>(xk, i_ltp, ps, seqb,
                                                            nullptr, pg_rk, pg_b);
                k_link_mfma<true><<<NL / 4, 256, 0, stream>>>(seqb, i_p2l, ls, at_w, at_b,
                                                              lg_k, lg_rk, lg_b, xk, pg_k,
                                                              pg_b);
            } else {
                k_path_mfma<2><<<NF / 64, 256, 0, stream>>>(xk, i_ltp, ps, nullptr,
                                                            seqfL, pg_rk, pg_b);
            }
        }
        k_kan<1><<<NF * 8 / 256, 256, 0, stream>>>(seqfL, i_ltp, f_cap, k1_sp, k1_ba,
                                                   k1_bi, k2_sp, k2_ba, k2_bi, out);
    } else {
        for (int it = 0; it < 12; ++it) {
            k_path_mfma<0><<<NF / 64, 256, 0, stream>>>(xk, i_ltp, ps, nullptr,
                                                        seq32, pg_rk, pg_b);
            if (it < 11)
                k_link_mfma<false><<<NL / 4, 256, 0, stream>>>(seq32, i_p2l, ls, at_w, at_b,
                                                               lg_k, lg_rk, lg_b, xk, pg_k,
                                                               pg_b);
        }
        k_kan<0><<<NF * 8 / 256, 256, 0, stream>>>(seq32, i_ltp, f_cap, k1_sp, k1_ba,
                                                   k1_bi, k2_sp, k2_ba, k2_bi, out);
    }
}

// Round 10
// 482.735 us; speedup vs baseline: 1.9929x; 1.0327x over previous
//
#include <hip/hip_runtime.h>
#include <cstdint>

#define NF 65536
#define PL 8
#define NL 4096
#define PPL 128
#define XKS 64  // padded xk record stride (floats): 256 B, cacheline-aligned

typedef _Float16 f16x4 __attribute__((ext_vector_type(4)));
typedef _Float16 f16x8v __attribute__((ext_vector_type(8)));
typedef float f32x4 __attribute__((ext_vector_type(4)));

__device__ __forceinline__ float sigm(float v) { return 1.0f / (1.0f + __expf(-v)); }
__device__ __forceinline__ float tanhfast(float v) {
    float e = __expf(2.0f * v);
    return 1.0f - 2.0f / (e + 1.0f);
}
__device__ __forceinline__ float seluf(float x) {
    return x > 0.0f ? 1.0507009873554805f * x : 1.7580993408473766f * (__expf(x) - 1.0f);
}
__device__ __forceinline__ unsigned short f2bf(float x) {
    unsigned u = __float_as_uint(x);
    u += 0x7fffu + ((u >> 16) & 1u);
    return (unsigned short)(u >> 16);
}
__device__ __forceinline__ float bfu(unsigned short us) {
    return __uint_as_float((unsigned)us << 16);
}
// hi/lo split: x ~= hi + lo with ~22 combined mantissa bits
__device__ __forceinline__ void splitf(float x, _Float16& hi, _Float16& lo) {
    _Float16 h = (_Float16)x;
    hi = h;
    lo = (_Float16)(x - (float)h);
}
// compensated matvec: A*B with A=Ah+Al, B=Bh+Bl (drop Al*Bl ~ 2^-22)
__device__ __forceinline__ f32x4 mfma3(f16x4 Ah, f16x4 Al, f16x4 Bh, f16x4 Bl,
                                       f32x4 acc) {
    acc = __builtin_amdgcn_mfma_f32_16x16x16f16(Ah, Bh, acc, 0, 0, 0);
    acc = __builtin_amdgcn_mfma_f32_16x16x16f16(Al, Bh, acc, 0, 0, 0);
    acc = __builtin_amdgcn_mfma_f32_16x16x16f16(Ah, Bl, acc, 0, 0, 0);
    return acc;
}

// Sparse cubic B-spline: 4 active bases at local u, interval idx. Uniform knots
// t_j = (j-3)*0.4 - 1 (identical to jnp _knots pyramid; closed-form is exact).
__device__ __forceinline__ int bspline4(float xx, float& B0, float& B1, float& B2,
                                        float& B3) {
    const float KN0 = (0 - 3) * 0.4f - 1.0f;    // t_0  = -2.2
    float s = (xx - KN0) * 2.5f;
    int idx = (int)floorf(s);
    bool valid = (idx >= 0) && (idx <= 10);     // outside [t_0, t_11): all bases 0
    idx = min(max(idx, 0), 10);
    float tI = (float)(idx - 3) * 0.4f - 1.0f;
    float u = (xx - tI) * 2.5f;
    float um = 1.0f - u;
    float u2 = u * u, u3 = u2 * u;
    B0 = um * um * um * (1.0f / 6.0f);
    B1 = 0.5f * u3 - u2 + (2.0f / 3.0f);
    B2 = -0.5f * u3 + 0.5f * u2 + 0.5f * u + (1.0f / 6.0f);
    B3 = u3 * (1.0f / 6.0f);
    if (!valid) { B0 = 0.f; B1 = 0.f; B2 = 0.f; B3 = 0.f; }
    return idx;
}

// ---------------- S1: per-link load ----------------
__global__ __launch_bounds__(256) void k_load(const int* __restrict__ p2l,
                                              const float* __restrict__ ft,
                                              const float* __restrict__ cap,
                                              float* __restrict__ load) {
    int gid = blockIdx.x * 256 + threadIdx.x;
    int link = gid >> 6;
    int lane = threadIdx.x & 63;
    const int2* b2 = (const int2*)(p2l + (size_t)link * PPL * 2);
    int2 v0 = b2[lane];
    int2 v1 = b2[lane + 64];
    float s = ft[v0.x] + ft[v1.x];
#pragma unroll
    for (int off = 32; off; off >>= 1) s += __shfl_xor(s, off);
    if (lane == 0) load[link] = s / (cap[link] * 1e9f);
}

// ---------------- S2: flow encoder -> path_state ----------------
__global__ __launch_bounds__(256) void k_flow_enc(
    const float* __restrict__ tr, const float* __restrict__ pk,
    const float* __restrict__ ppb, const float* __restrict__ bpb,
    const float* __restrict__ psz, const float* __restrict__ p90,
    const float* __restrict__ rate, const float* __restrict__ ipgm,
    const float* __restrict__ ibg, const float* __restrict__ ipgv,
    const float* __restrict__ ftype, const int* __restrict__ flen,
    const float* __restrict__ w1, const float* __restrict__ b1,
    const float* __restrict__ w2, const float* __restrict__ b2,
    float* __restrict__ ps) {
    __shared__ float sw1[13 * 16], sb1[16], sw2[256], sb2[16];
    int tid = threadIdx.x;
    if (tid < 208) sw1[tid] = w1[tid];
    sw2[tid] = w2[tid];
    if (tid < 16) { sb1[tid] = b1[tid]; sb2[tid] = b2[tid]; }
    __syncthreads();
    int f = blockIdx.x * 256 + tid;
    float feat[13];
    feat[0] = (tr[f] - 0.5f) * 2.0f;
    feat[1] = (pk[f] - 0.5f) * 2.0f;
    feat[2] = (ibg[f] - 0.5f) * 2.0f;
    feat[3] = (rate[f] - 0.5f) * 2.0f;
    feat[4] = (p90[f] - 0.5f) * 2.0f;
    feat[5] = (psz[f] - 0.5f) * 2.0f;
    feat[6] = (bpb[f] - 0.5f) * 2.0f;
    feat[7] = (ipgm[f] - 0.5f) * 2.0f;
    feat[8] = (ipgv[f] - 0.5f) * 2.0f;
    feat[9] = (ppb[f] - 0.5f) * 2.0f;
    feat[10] = (float)flen[f];
    float2 ft2 = ((const float2*)ftype)[f];
    feat[11] = ft2.x;
    feat[12] = ft2.y;
    float t1[16];
#pragma unroll
    for (int u = 0; u < 16; ++u) {
        float a = sb1[u];
#pragma unroll
        for (int i = 0; i < 13; ++i) a += feat[i] * sw1[i * 16 + u];
        t1[u] = seluf(a);
    }
    float out[16];
#pragma unroll
    for (int u = 0; u < 16; ++u) {
        float a = sb2[u];
#pragma unroll
        for (int i = 0; i < 16; ++i) a += t1[i] * sw2[i * 16 + u];
        out[u] = seluf(a);
    }
    float4* o4 = (float4*)(ps + (size_t)f * 16);
    const float4* s4 = (const float4*)out;
#pragma unroll
    for (int q = 0; q < 4; ++q) o4[q] = s4[q];
}

// ---------------- S3: link encoder -> link_state (+ xk fold) ----------------
__global__ __launch_bounds__(256) void k_link_enc(
    const float* __restrict__ cap, const float* __restrict__ load,
    const float* __restrict__ mll,
    const float* __restrict__ w1, const float* __restrict__ b1,
    const float* __restrict__ w2, const float* __restrict__ b2,
    float* __restrict__ ls, float* __restrict__ xk,
    const float* __restrict__ pgk, const float* __restrict__ pgb) {
    int l = blockIdx.x * 256 + threadIdx.x;
    if (l >= NL) return;
    float f0 = (cap[l] - 5.0f) * 0.25f;
    float f1 = load[l];
    float f2 = f1 / mll[0];
    float f3 = 8.0f / 32768.0f;
    float t1[16];
#pragma unroll
    for (int u = 0; u < 16; ++u) {
        float a = b1[u] + f0 * w1[u] + f1 * w1[16 + u] + f2 * w1[32 + u] + f3 * w1[48 + u];
        t1[u] = seluf(a);
    }
    float out[16];
#pragma unroll
    for (int u = 0; u < 16; ++u) {
        float a = b2[u];
#pragma unroll
        for (int i = 0; i < 16; ++i) a += t1[i] * w2[i * 16 + u];
        out[u] = seluf(a);
    }
    float4* o4 = (float4*)(ls + (size_t)l * 16);
    const float4* s4 = (const float4*)out;
#pragma unroll
    for (int q = 0; q < 4; ++q) o4[q] = s4[q];
    for (int u = 0; u < 48; ++u) {
        float a = pgb[u];
#pragma unroll
        for (int i = 0; i < 16; ++i) a += out[i] * pgk[i * 48 + u];
        xk[(size_t)l * XKS + u] = a;
    }
}

// ---------------- K1: path GRU via MFMA (round-6 proven) ----------------
template <int MODE>
__global__ __launch_bounds__(256) void k_path_mfma(
    const float* __restrict__ xk, const int* __restrict__ ltp,
    float* __restrict__ ps, unsigned short* __restrict__ seqb,
    float* __restrict__ seqf,
    const float* __restrict__ grk, const float* __restrict__ gb) {
    int tid = threadIdx.x;
    int lane = tid & 63;
    int fcol = lane & 15, q = lane >> 4;
    int f = blockIdx.x * 64 + (tid >> 6) * 16 + fcol;
    f16x4 Az, Ar, Ac;
#pragma unroll
    for (int j = 0; j < 4; ++j) {
        Az[j] = (_Float16)grk[(q * 4 + j) * 48 + fcol];
        Ar[j] = (_Float16)grk[(q * 4 + j) * 48 + 16 + fcol];
        Ac[j] = (_Float16)grk[(q * 4 + j) * 48 + 32 + fcol];
    }
    float4 bgz = *(const float4*)(gb + 48 + q * 4);
    float4 bgr = *(const float4*)(gb + 64 + q * 4);
    float4 bgc = *(const float4*)(gb + 80 + q * 4);
    float4 h0 = *(const float4*)(ps + (size_t)f * 16 + q * 4);
    f32x4 h = {h0.x, h0.y, h0.z, h0.w};
    int4 lt0 = *(const int4*)(ltp + (size_t)f * 8);
    int4 lt1 = *(const int4*)(ltp + (size_t)f * 8 + 4);
    if (MODE == 0) {
        *(float4*)(seqf + (size_t)f * 9 * 16 + q * 4) = h0;
    } else if (MODE == 1) {
        ushort4 u4;
        u4.x = f2bf(h[0]); u4.y = f2bf(h[1]); u4.z = f2bf(h[2]); u4.w = f2bf(h[3]);
        *(ushort4*)(seqb + (size_t)f * 16 + q * 4) = u4;  // row 0
    }
#pragma unroll
    for (int t = 0; t < 8; ++t) {
        int lk = (t == 0) ? lt0.x : (t == 1) ? lt0.y : (t == 2) ? lt0.z : (t == 3) ? lt0.w
               : (t == 4) ? lt1.x : (t == 5) ? lt1.y : (t == 6) ? lt1.z : lt1.w;
        const float* xb = xk + (size_t)lk * XKS;
        float4 xz = *(const float4*)(xb + q * 4);
        float4 xr = *(const float4*)(xb + 16 + q * 4);
        float4 xc = *(const float4*)(xb + 32 + q * 4);
        f16x4 hb;
#pragma unroll
        for (int r = 0; r < 4; ++r) hb[r] = (_Float16)h[r];
        f32x4 accZ = {xz.x + bgz.x, xz.y + bgz.y, xz.z + bgz.z, xz.w + bgz.w};
        f32x4 accR = {xr.x + bgr.x, xr.y + bgr.y, xr.z + bgr.z, xr.w + bgr.w};
        f32x4 accC = {bgc.x, bgc.y, bgc.z, bgc.w};
        accZ = __builtin_amdgcn_mfma_f32_16x16x16f16(Az, hb, accZ, 0, 0, 0);
        accR = __builtin_amdgcn_mfma_f32_16x16x16f16(Ar, hb, accR, 0, 0, 0);
        accC = __builtin_amdgcn_mfma_f32_16x16x16f16(Ac, hb, accC, 0, 0, 0);
        float xc0 = xc.x, xc1 = xc.y, xc2 = xc.z, xc3 = xc.w;
        {
            float z = sigm(accZ[0]), rr = sigm(accR[0]);
            float c = tanhfast(xc0 + rr * accC[0]);
            h[0] = z * h[0] + (1.0f - z) * c;
            z = sigm(accZ[1]); rr = sigm(accR[1]);
            c = tanhfast(xc1 + rr * accC[1]);
            h[1] = z * h[1] + (1.0f - z) * c;
            z = sigm(accZ[2]); rr = sigm(accR[2]);
            c = tanhfast(xc2 + rr * accC[2]);
            h[2] = z * h[2] + (1.0f - z) * c;
            z = sigm(accZ[3]); rr = sigm(accR[3]);
            c = tanhfast(xc3 + rr * accC[3]);
            h[3] = z * h[3] + (1.0f - z) * c;
        }
        if (MODE == 0) {
            float4 st = {h[0], h[1], h[2], h[3]};
            *(float4*)(seqf + ((size_t)f * 9 + t + 1) * 16 + q * 4) = st;
        } else if (MODE == 1) {
            if (t < 7) {
                ushort4 u4;
                u4.x = f2bf(h[0]); u4.y = f2bf(h[1]); u4.z = f2bf(h[2]); u4.w = f2bf(h[3]);
                *(ushort4*)(seqb + ((size_t)(t + 1) * NF + f) * 16 + q * 4) = u4;
            }
        } else {
            float4 st = {h[0], h[1], h[2], h[3]};
            *(float4*)(seqf + ((size_t)f * 8 + t) * 16 + q * 4) = st;
        }
    }
    if (MODE != 2) {
        float4 st = {h[0], h[1], h[2], h[3]};
        *(float4*)(ps + (size_t)f * 16 + q * 4) = st;
    }
}

// ---------------- K2: link update via MFMA with hi/lo compensation ----------------
// Round-8 proven; hoisted gathers (math-identical reorder).
template <bool BF16>
__global__ __launch_bounds__(256) void k_link_mfma(
    const void* __restrict__ seqv, const int* __restrict__ p2l,
    float* __restrict__ ls,
    const float* __restrict__ aw, const float* __restrict__ ab,
    const float* __restrict__ gk, const float* __restrict__ grk,
    const float* __restrict__ gb,
    float* __restrict__ xk, const float* __restrict__ pgk,
    const float* __restrict__ pgb) {
    int tid = threadIdx.x;
    int lane = tid & 63;
    int m = lane & 15, q = lane >> 4;
    int link = blockIdx.x * 4 + (tid >> 6);
    f16x4 AatH, AatL, Agk0H, Agk0L, Agk1H, Agk1L, Agk2H, Agk2L;
    f16x4 Agr0H, Agr0L, Agr1H, Agr1L, Agr2H, Agr2L;
    f16x4 Apg0H, Apg0L, Apg1H, Apg1L, Apg2H, Apg2L;
#pragma unroll
    for (int j = 0; j < 4; ++j) {
        int k = q * 4 + j;
        _Float16 hh, ll;
        splitf(aw[k * 16 + m], hh, ll); AatH[j] = hh; AatL[j] = ll;
        splitf(gk[k * 48 + m], hh, ll); Agk0H[j] = hh; Agk0L[j] = ll;
        splitf(gk[k * 48 + 16 + m], hh, ll); Agk1H[j] = hh; Agk1L[j] = ll;
        splitf(gk[k * 48 + 32 + m], hh, ll); Agk2H[j] = hh; Agk2L[j] = ll;
        splitf(grk[k * 48 + m], hh, ll); Agr0H[j] = hh; Agr0L[j] = ll;
        splitf(grk[k * 48 + 16 + m], hh, ll); Agr1H[j] = hh; Agr1L[j] = ll;
        splitf(grk[k * 48 + 32 + m], hh, ll); Agr2H[j] = hh; Agr2L[j] = ll;
        splitf(pgk[k * 48 + m], hh, ll); Apg0H[j] = hh; Apg0L[j] = ll;
        splitf(pgk[k * 48 + 16 + m], hh, ll); Apg1H[j] = hh; Apg1L[j] = ll;
        splitf(pgk[k * 48 + 32 + m], hh, ll); Apg2H[j] = hh; Apg2L[j] = ll;
    }
    float4 abf = *(const float4*)(ab + q * 4);
    float4 hq = *(const float4*)(ls + (size_t)link * 16 + q * 4);
    const int2* ppb = (const int2*)p2l + (size_t)link * PPL;
    int2 pp[8];
#pragma unroll
    for (int ch = 0; ch < 8; ++ch) pp[ch] = ppb[ch * 16 + m];
    f32x4 gp[8];
#pragma unroll
    for (int ch = 0; ch < 8; ++ch) {
        if (BF16) {
            const unsigned short* sp =
                (const unsigned short*)seqv + ((size_t)pp[ch].y * NF + pp[ch].x) * 16 + q * 4;
            ushort4 u4 = *(const ushort4*)sp;
            gp[ch][0] = bfu(u4.x); gp[ch][1] = bfu(u4.y);
            gp[ch][2] = bfu(u4.z); gp[ch][3] = bfu(u4.w);
        } else {
            float4 v = *(const float4*)((const float*)seqv +
                                        ((size_t)pp[ch].x * 9 + pp[ch].y) * 16 + q * 4);
            gp[ch][0] = v.x; gp[ch][1] = v.y; gp[ch][2] = v.z; gp[ch][3] = v.w;
        }
    }
    f32x4 macc = {0.f, 0.f, 0.f, 0.f};
#pragma unroll
    for (int ch = 0; ch < 8; ++ch) {
        float p0 = gp[ch][0], p1 = gp[ch][1], p2 = gp[ch][2], p3 = gp[ch][3];
        f16x4 BpgH, BpgL;
        {
            _Float16 hh, ll;
            splitf(p0, hh, ll); BpgH[0] = hh; BpgL[0] = ll;
            splitf(p1, hh, ll); BpgH[1] = hh; BpgL[1] = ll;
            splitf(p2, hh, ll); BpgH[2] = hh; BpgL[2] = ll;
            splitf(p3, hh, ll); BpgH[3] = hh; BpgL[3] = ll;
        }
        f32x4 at = {abf.x, abf.y, abf.z, abf.w};
        at = mfma3(AatH, AatL, BpgH, BpgL, at);
        float a0 = at[0] > 0.f ? at[0] : 0.01f * at[0];
        float a1 = at[1] > 0.f ? at[1] : 0.01f * at[1];
        float a2 = at[2] > 0.f ? at[2] : 0.01f * at[2];
        float a3 = at[3] > 0.f ? at[3] : 0.01f * at[3];
        float mx = fmaxf(fmaxf(a0, a1), fmaxf(a2, a3));
        mx = fmaxf(mx, __shfl_xor(mx, 16));
        mx = fmaxf(mx, __shfl_xor(mx, 32));
        float e0 = __expf(a0 - mx), e1 = __expf(a1 - mx);
        float e2 = __expf(a2 - mx), e3 = __expf(a3 - mx);
        float s = e0 + e1 + e2 + e3;
        s += __shfl_xor(s, 16);
        s += __shfl_xor(s, 32);
        float inv = 1.0f / s;
        macc[0] += e0 * inv * p0;
        macc[1] += e1 * inv * p1;
        macc[2] += e2 * inv * p2;
        macc[3] += e3 * inv * p3;
    }
#pragma unroll
    for (int off = 1; off < 16; off <<= 1) {
        macc[0] += __shfl_xor(macc[0], off);
        macc[1] += __shfl_xor(macc[1], off);
        macc[2] += __shfl_xor(macc[2], off);
        macc[3] += __shfl_xor(macc[3], off);
    }
    f16x4 BmsgH, BmsgL, BhH, BhL;
    {
        _Float16 hh, ll;
        splitf(macc[0], hh, ll); BmsgH[0] = hh; BmsgL[0] = ll;
        splitf(macc[1], hh, ll); BmsgH[1] = hh; BmsgL[1] = ll;
        splitf(macc[2], hh, ll); BmsgH[2] = hh; BmsgL[2] = ll;
        splitf(macc[3], hh, ll); BmsgH[3] = hh; BmsgL[3] = ll;
        splitf(hq.x, hh, ll); BhH[0] = hh; BhL[0] = ll;
        splitf(hq.y, hh, ll); BhH[1] = hh; BhL[1] = ll;
        splitf(hq.z, hh, ll); BhH[2] = hh; BhL[2] = ll;
        splitf(hq.w, hh, ll); BhH[3] = hh; BhL[3] = ll;
    }
    float4 bz = *(const float4*)(gb + q * 4);
    float4 br = *(const float4*)(gb + 16 + q * 4);
    float4 bc = *(const float4*)(gb + 32 + q * 4);
    float4 hz4 = *(const float4*)(gb + 48 + q * 4);
    float4 hr4 = *(const float4*)(gb + 64 + q * 4);
    float4 hc4 = *(const float4*)(gb + 80 + q * 4);
    f32x4 az = {bz.x, bz.y, bz.z, bz.w};
    f32x4 ar = {br.x, br.y, br.z, br.w};
    f32x4 ac = {bc.x, bc.y, bc.z, bc.w};
    f32x4 gz = {hz4.x, hz4.y, hz4.z, hz4.w};
    f32x4 gr = {hr4.x, hr4.y, hr4.z, hr4.w};
    f32x4 gc = {hc4.x, hc4.y, hc4.z, hc4.w};
    az = mfma3(Agk0H, Agk0L, BmsgH, BmsgL, az);
    ar = mfma3(Agk1H, Agk1L, BmsgH, BmsgL, ar);
    ac = mfma3(Agk2H, Agk2L, BmsgH, BmsgL, ac);
    gz = mfma3(Agr0H, Agr0L, BhH, BhL, gz);
    gr = mfma3(Agr1H, Agr1L, BhH, BhL, gr);
    gc = mfma3(Agr2H, Agr2L, BhH, BhL, gc);
    float hn0, hn1, hn2, hn3;
    {
        float z = sigm(az[0] + gz[0]), rr = sigm(ar[0] + gr[0]);
        float c = tanhfast(ac[0] + rr * gc[0]);
        hn0 = z * hq.x + (1.0f - z) * c;
        z = sigm(az[1] + gz[1]); rr = sigm(ar[1] + gr[1]);
        c = tanhfast(ac[1] + rr * gc[1]);
        hn1 = z * hq.y + (1.0f - z) * c;
        z = sigm(az[2] + gz[2]); rr = sigm(ar[2] + gr[2]);
        c = tanhfast(ac[2] + rr * gc[2]);
        hn2 = z * hq.z + (1.0f - z) * c;
        z = sigm(az[3] + gz[3]); rr = sigm(ar[3] + gr[3]);
        c = tanhfast(ac[3] + rr * gc[3]);
        hn3 = z * hq.w + (1.0f - z) * c;
    }
    if (m == 0) {
        float4 st = {hn0, hn1, hn2, hn3};
        *(float4*)(ls + (size_t)link * 16 + q * 4) = st;
    }
    f16x4 BhnH, BhnL;
    {
        _Float16 hh, ll;
        splitf(hn0, hh, ll); BhnH[0] = hh; BhnL[0] = ll;
        splitf(hn1, hh, ll); BhnH[1] = hh; BhnL[1] = ll;
        splitf(hn2, hh, ll); BhnH[2] = hh; BhnL[2] = ll;
        splitf(hn3, hh, ll); BhnH[3] = hh; BhnL[3] = ll;
    }
    float4 pb0 = *(const float4*)(pgb + q * 4);
    float4 pb1 = *(const float4*)(pgb + 16 + q * 4);
    float4 pb2 = *(const float4*)(pgb + 32 + q * 4);
    f32x4 x0 = {pb0.x, pb0.y, pb0.z, pb0.w};
    f32x4 x1 = {pb1.x, pb1.y, pb1.z, pb1.w};
    f32x4 x2 = {pb2.x, pb2.y, pb2.z, pb2.w};
    x0 = mfma3(Apg0H, Apg0L, BhnH, BhnL, x0);
    x1 = mfma3(Apg1H, Apg1L, BhnH, BhnL, x1);
    x2 = mfma3(Apg2H, Apg2L, BhnH, BhnL, x2);
    if (m == 0) {
        float4 s0 = {x0[0], x0[1], x0[2], x0[3]};
        float4 s1 = {x1[0], x1[1], x1[2], x1[3]};
        float4 s2 = {x2[0], x2[1], x2[2], x2[3]};
        float* xb = xk + (size_t)link * XKS;
        *(float4*)(xb + q * 4) = s0;
        *(float4*)(xb + 16 + q * 4) = s1;
        *(float4*)(xb + 32 + q * 4) = s2;
    }
}

// ---------------- K4: KAN readout (round-8 proven structure, f16 tables) ----------------
template <int M>
__global__ __launch_bounds__(256) void k_kan(
    const float* __restrict__ seqf, const int* __restrict__ ltp,
    const float* __restrict__ cap,
    const float* __restrict__ sp1, const float* __restrict__ ba1,
    const float* __restrict__ bi1,
    const float* __restrict__ sp2, const float* __restrict__ ba2,
    const float* __restrict__ bi2,
    float* __restrict__ out) {
    __shared__ _Float16 s1h[16 * 14 * 16];  // [i][idx pad14][u] f16 (halved LDS traffic)
    __shared__ _Float16 sba1h[256];         // [i][u] f16
    __shared__ float s2q[16 * 11 * 4];      // [i][idx11][b] f32 (zero-padded window)
    __shared__ float sbi1[16], sba2[16];
    int tid = threadIdx.x;
    for (int k = tid; k < 16 * 14 * 16; k += 256) {
        int u = k & 15;
        int r = (k >> 4) % 14;
        int i = k / (14 * 16);
        int jj = r - 3;
        s1h[k] = (_Float16)((jj >= 0 && jj < 8) ? sp1[(i * 8 + jj) * 16 + u] : 0.0f);
    }
    sba1h[tid] = (_Float16)ba1[tid];
    for (int k = tid; k < 16 * 11 * 4; k += 256) {
        int b = k & 3;
        int idx = (k >> 2) % 11;
        int i = k / 44;
        int jj = idx + b - 3;
        s2q[k] = (jj >= 0 && jj < 8) ? sp2[i * 8 + jj] : 0.0f;
    }
    if (tid < 16) { sbi1[tid] = bi1[tid]; sba2[tid] = ba2[tid]; }
    __syncthreads();
    int gt = blockIdx.x * 256 + tid;
    int f = gt >> 3, t = gt & 7;
    float x[16];
    {
        const float4* xv = (M == 0)
            ? (const float4*)(seqf + ((size_t)f * 9 + 1 + t) * 16)
            : (const float4*)(seqf + ((size_t)f * 8 + t) * 16);
        float4* xr = (float4*)x;
        xr[0] = xv[0]; xr[1] = xv[1]; xr[2] = xv[2]; xr[3] = xv[3];
    }
    float hh[16];
#pragma unroll
    for (int u = 0; u < 16; ++u) hh[u] = sbi1[u];
#pragma unroll
    for (int i = 0; i < 16; ++i) {
        float B0, B1, B2, B3;
        int idx = bspline4(x[i], B0, B1, B2, B3);
        const _Float16* rb = s1h + (i * 14 + idx) * 16;
        f16x8v r0a = *(const f16x8v*)(rb);
        f16x8v r0b = *(const f16x8v*)(rb + 8);
        f16x8v r1a = *(const f16x8v*)(rb + 16);
        f16x8v r1b = *(const f16x8v*)(rb + 24);
        f16x8v r2a = *(const f16x8v*)(rb + 32);
        f16x8v r2b = *(const f16x8v*)(rb + 40);
        f16x8v r3a = *(const f16x8v*)(rb + 48);
        f16x8v r3b = *(const f16x8v*)(rb + 56);
        f16x8v sa = *(const f16x8v*)(sba1h + i * 16);
        f16x8v sb = *(const f16x8v*)(sba1h + i * 16 + 8);
        float sil = x[i] * sigm(x[i]);
#pragma unroll
        for (int u = 0; u < 8; ++u) {
            hh[u] += B0 * (float)r0a[u] + B1 * (float)r1a[u] + B2 * (float)r2a[u] +
                     B3 * (float)r3a[u] + sil * (float)sa[u];
            hh[8 + u] += B0 * (float)r0b[u] + B1 * (float)r1b[u] + B2 * (float)r2b[u] +
                         B3 * (float)r3b[u] + sil * (float)sb[u];
        }
    }
    float occ = bi2[0];
#pragma unroll
    for (int i = 0; i < 16; ++i) {
        float B0, B1, B2, B3;
        int idx = bspline4(hh[i], B0, B1, B2, B3);
        float4 rw = *(const float4*)(s2q + (i * 11 + idx) * 4);
        occ += B0 * rw.x + B1 * rw.y + B2 * rw.z + B3 * rw.w;
        occ += hh[i] * sigm(hh[i]) * sba2[i];
    }
    int lk = ltp[(size_t)f * 8 + t];
    float val = occ / cap[lk];
#pragma unroll
    for (int off = 4; off; off >>= 1) val += __shfl_xor(val, off, 8);
    if (t == 0) out[f] = val;
}

extern "C" void kernel_launch(void* const* d_in, const int* in_sizes, int n_in,
                              void* d_out, int out_size, void* d_ws, size_t ws_size,
                              hipStream_t stream) {
    const float* f_tr   = (const float*)d_in[0];
    const float* f_pk   = (const float*)d_in[1];
    const float* f_ppb  = (const float*)d_in[2];
    const float* f_bpb  = (const float*)d_in[3];
    const float* f_psz  = (const float*)d_in[4];
    const float* f_p90  = (const float*)d_in[5];
    const float* f_rate = (const float*)d_in[6];
    const float* f_ipgm = (const float*)d_in[7];
    const float* f_ibg  = (const float*)d_in[8];
    const float* f_ipgv = (const float*)d_in[9];
    const float* f_type = (const float*)d_in[10];
    const float* f_cap  = (const float*)d_in[11];
    const float* f_mll  = (const float*)d_in[12];
    const int*   i_flen = (const int*)d_in[13];
    const int*   i_ltp  = (const int*)d_in[15];
    const int*   i_p2l  = (const int*)d_in[16];
    const float* fe_w1 = (const float*)d_in[17];
    const float* fe_b1 = (const float*)d_in[18];
    const float* fe_w2 = (const float*)d_in[19];
    const float* fe_b2 = (const float*)d_in[20];
    const float* le_w1 = (const float*)d_in[21];
    const float* le_b1 = (const float*)d_in[22];
    const float* le_w2 = (const float*)d_in[23];
    const float* le_b2 = (const float*)d_in[24];
    const float* at_w  = (const float*)d_in[25];
    const float* at_b  = (const float*)d_in[26];
    const float* pg_k  = (const float*)d_in[27];
    const float* pg_rk = (const float*)d_in[28];
    const float* pg_b  = (const float*)d_in[29];
    const float* lg_k  = (const float*)d_in[30];
    const float* lg_rk = (const float*)d_in[31];
    const float* lg_b  = (const float*)d_in[32];
    const float* k1_sp = (const float*)d_in[33];
    const float* k1_ba = (const float*)d_in[34];
    const float* k1_bi = (const float*)d_in[35];
    const float* k2_sp = (const float*)d_in[36];
    const float* k2_ba = (const float*)d_in[37];
    const float* k2_bi = (const float*)d_in[38];

    float* ws = (float*)d_ws;
    float* ps   = ws;
    float* ls   = ps + (size_t)NF * 16;
    float* xk   = ls + (size_t)NL * 16;
    float* load = xk + (size_t)NL * XKS;
    float* tail = load + NL;
    size_t head_bytes = (size_t)(tail - ws) * 4;
    unsigned short* seqb = (unsigned short*)tail;          // bf16 [8][NF][16]
    size_t seqb_elems = (size_t)NF * 8 * 16;
    float* seqfL = (float*)(seqb + seqb_elems);            // f32 [NF][8][16]
    size_t need_bf = head_bytes + seqb_elems * 2 + (size_t)NF * 8 * 16 * 4;
    float* seq32 = tail;                                   // fallback f32 [NF][9][16]
    bool bfp = ws_size >= need_bf;
    float* out = (float*)d_out;

    k_load<<<NL * 64 / 256, 256, 0, stream>>>(i_p2l, f_tr, f_cap, load);
    k_flow_enc<<<NF / 256, 256, 0, stream>>>(f_tr, f_pk, f_ppb, f_bpb, f_psz, f_p90,
                                             f_rate, f_ipgm, f_ibg, f_ipgv, f_type,
                                             i_flen, fe_w1, fe_b1, fe_w2, fe_b2, ps);
    k_link_enc<<<NL / 256, 256, 0, stream>>>(f_cap, load, f_mll, le_w1, le_b1, le_w2,
                                             le_b2, ls, xk, pg_k, pg_b);
    if (bfp) {
        for (int it = 0; it < 12; ++it) {
            if (it < 11) {
                k_path_mfma<1><<<NF / 64, 256, 0, stream>>>(xk, i_ltp, ps, seqb,
                                                            nullptr, pg_rk, pg_b);
                k_link_mfma<true><<<NL / 4, 256, 0, stream>>>(seqb, i_p2l, ls, at_w, at_b,
                                                              lg_k, lg_rk, lg_b, xk, pg_k,
                                                              pg_b);
            } else {
                k_path_mfma<2><<<NF / 64, 256, 0, stream>>>(xk, i_ltp, ps, nullptr,
                                                            seqfL, pg_rk, pg_b);
            }
        }
        k_kan<1><<<NF * 8 / 256, 256, 0, stream>>>(seqfL, i_ltp, f_cap, k1_sp, k1_ba,
                                                   k1_bi, k2_sp, k2_ba, k2_bi, out);
    } else {
        for (int it = 0; it < 12; ++it) {
            k_path_mfma<0><<<NF / 64, 256, 0, stream>>>(xk, i_ltp, ps, nullptr,
                                                        seq32, pg_rk, pg_b);
            if (it < 11)
                k_link_mfma<false><<<NL / 4, 256, 0, stream>>>(seq32, i_p2l, ls, at_w, at_b,
                                                               lg_k, lg_rk, lg_b, xk, pg_k,
                                                               pg_b);
        }
        k_kan<0><<<NF * 8 / 256, 256, 0, stream>>>(seq32, i_ltp, f_cap, k1_sp, k1_ba,
                                                   k1_bi, k2_sp, k2_ba, k2_bi, out);
    }
}